// Round 6
// baseline (408.968 us; speedup 1.0000x reference)
//
#include <hip/hip_runtime.h>

#define BB 2
#define NN 32768
#define EN 32768

typedef unsigned int u32;
typedef __attribute__((ext_vector_type(8))) short bf16x8;
typedef __attribute__((ext_vector_type(4))) float f32x4;

union U4 { uint4 u; bf16x8 h; };

// ---------------------------------------------------------------------------
// f32 pair -> packed bf16 dword (RNE). HW instr on gfx950 when available.
// ---------------------------------------------------------------------------
#if defined(__has_builtin)
#if __has_builtin(__builtin_amdgcn_cvt_pk_bf16_f32)
#define HAVE_CVT_PK 1
#endif
#endif

#ifdef HAVE_CVT_PK
typedef __attribute__((ext_vector_type(2))) __bf16 bfv2;
__device__ __forceinline__ u32 pk2(float lo, float hi) {
    bfv2 v = __builtin_amdgcn_cvt_pk_bf16_f32(lo, hi);
    return __builtin_bit_cast(u32, v);
}
#else
__device__ __forceinline__ u32 pk2(float lo, float hi) {
    u32 a = __builtin_bit_cast(u32, lo);
    u32 b = __builtin_bit_cast(u32, hi);
    a += 0x7FFFu + ((a >> 16) & 1u);
    b += 0x7FFFu + ((b >> 16) & 1u);
    return (a >> 16) | (b & 0xFFFF0000u);
}
#endif

// ---------------------------------------------------------------------------
// Operand-swapped layer epilogue (NO LDS).
// Weights are the MFMA A-operand (m = out-feature), activations the
// B-operand (n = element). D C-layout: lane (n,q) holds out-feature q*4+r
// (D0, lo half) and 16+q*4+r (D1, hi half) of element n. Under the pi
// k-permutation (position (q,2i) <-> feat q*4+i, (q,2i+1) <-> feat q*4+i+16)
// the packed dword i = pk2(y_lo[i], y_hi[i]) IS the next layer's B-frag
// dword i -> layer-to-layer stays entirely in registers.
// LN stats for element n live across the 4 lanes (n, q=0..3): shfl_xor 16/32.
// ---------------------------------------------------------------------------
template<bool LN>
__device__ __forceinline__ bf16x8 transform(
    f32x4 D0, f32x4 D1,
    const float* __restrict__ bias,
    const float* __restrict__ lg, const float* __restrict__ lb, int q)
{
    float4 bl = *(const float4*)(bias + q*4);
    float4 bh = *(const float4*)(bias + q*4 + 16);
    float y0 = fmaxf(D0[0] + bl.x, 0.f), y1 = fmaxf(D0[1] + bl.y, 0.f);
    float y2 = fmaxf(D0[2] + bl.z, 0.f), y3 = fmaxf(D0[3] + bl.w, 0.f);
    float z0 = fmaxf(D1[0] + bh.x, 0.f), z1 = fmaxf(D1[1] + bh.y, 0.f);
    float z2 = fmaxf(D1[2] + bh.z, 0.f), z3 = fmaxf(D1[3] + bh.w, 0.f);
    if (LN) {
        float s = ((y0+y1)+(y2+y3)) + ((z0+z1)+(z2+z3));
        float s2 = 0.f;
        s2 = fmaf(y0,y0,s2); s2 = fmaf(y1,y1,s2); s2 = fmaf(y2,y2,s2); s2 = fmaf(y3,y3,s2);
        s2 = fmaf(z0,z0,s2); s2 = fmaf(z1,z1,s2); s2 = fmaf(z2,z2,s2); s2 = fmaf(z3,z3,s2);
        s  += __shfl_xor(s, 16);  s  += __shfl_xor(s, 32);
        s2 += __shfl_xor(s2, 16); s2 += __shfl_xor(s2, 32);
        float mu  = s * (1.f/32.f);
        float var = fmaf(-mu, mu, s2 * (1.f/32.f));
        float rs  = rsqrtf(var + 1e-5f);
        float4 gl = *(const float4*)(lg + q*4);
        float4 gh = *(const float4*)(lg + q*4 + 16);
        float4 ol = *(const float4*)(lb + q*4);
        float4 oh = *(const float4*)(lb + q*4 + 16);
        float sl0 = rs*gl.x, sl1 = rs*gl.y, sl2 = rs*gl.z, sl3 = rs*gl.w;
        float sh0 = rs*gh.x, sh1 = rs*gh.y, sh2 = rs*gh.z, sh3 = rs*gh.w;
        y0 = fmaf(y0, sl0, fmaf(-mu, sl0, ol.x));
        y1 = fmaf(y1, sl1, fmaf(-mu, sl1, ol.y));
        y2 = fmaf(y2, sl2, fmaf(-mu, sl2, ol.z));
        y3 = fmaf(y3, sl3, fmaf(-mu, sl3, ol.w));
        z0 = fmaf(z0, sh0, fmaf(-mu, sh0, oh.x));
        z1 = fmaf(z1, sh1, fmaf(-mu, sh1, oh.y));
        z2 = fmaf(z2, sh2, fmaf(-mu, sh2, oh.z));
        z3 = fmaf(z3, sh3, fmaf(-mu, sh3, oh.w));
    }
    U4 c;
    c.u.x = pk2(y0, z0); c.u.y = pk2(y1, z1);
    c.u.z = pk2(y2, z2); c.u.w = pk2(y3, z3);
    return c.h;
}

// ---------------------------------------------------------------------------
// Wave-level deep MLP, fully register-resident between layers.
// Packed weights Wp (pi layout, rows = out-features):
//   [Bin 32 rows x KT*16 dw] [Bh 32 layers x 32 rows x 16 dw] [Bo 16 x 16 dw]
// A-frag of lane (n,q) = uint4 at row n (and n+16 for the hi half), dwords
// q*4..q*4+3 — identical addressing to the old B-frag loads.
// ---------------------------------------------------------------------------
template<int KT, bool LN>
__device__ __forceinline__ f32x4 mlp_core(
    const bf16x8* b_in, const u32* __restrict__ Wp,
    const float* __restrict__ bin, const float* __restrict__ bh,
    const float* __restrict__ lng, const float* __restrict__ lnb,
    int n, int q)
{
    const u32* Bh = Wp + 32*KT*16;
    const u32* Bo = Bh + 16384;
    U4 c;
    f32x4 D0 = {0.f,0.f,0.f,0.f}, D1 = {0.f,0.f,0.f,0.f};
    #pragma unroll
    for (int T = 0; T < KT; ++T) {
        c.u = *(const uint4*)(Wp + (size_t)n*(KT*16) + T*16 + q*4);      bf16x8 a0 = c.h;
        c.u = *(const uint4*)(Wp + (size_t)(n+16)*(KT*16) + T*16 + q*4); bf16x8 a1 = c.h;
        D0 = __builtin_amdgcn_mfma_f32_16x16x32_bf16(a0, b_in[T], D0, 0, 0, 0);
        D1 = __builtin_amdgcn_mfma_f32_16x16x32_bf16(a1, b_in[T], D1, 0, 0, 0);
    }
    // prefetch layer-0 weights before the input epilogue
    c.u = *(const uint4*)(Bh + n*16 + q*4);       bf16x8 w0 = c.h;
    c.u = *(const uint4*)(Bh + (n+16)*16 + q*4);  bf16x8 w1 = c.h;
    bf16x8 bb = transform<LN>(D0, D1, bin, lng, lnb, q);
    #pragma unroll 1
    for (int l = 0; l < 32; ++l) {
        const int lnx = (l+1 < 32) ? l+1 : 31;
        const u32* Bn = Bh + lnx*512;
        c.u = *(const uint4*)(Bn + n*16 + q*4);       bf16x8 nw0 = c.h;
        c.u = *(const uint4*)(Bn + (n+16)*16 + q*4);  bf16x8 nw1 = c.h;
        f32x4 Z = {0.f,0.f,0.f,0.f};
        f32x4 E0 = __builtin_amdgcn_mfma_f32_16x16x32_bf16(w0, bb, Z, 0, 0, 0);
        f32x4 E1 = __builtin_amdgcn_mfma_f32_16x16x32_bf16(w1, bb, Z, 0, 0, 0);
        bb = transform<LN>(E0, E1, bh + l*32,
                           lng + (l+1)*32, lnb + (l+1)*32, q);
        w0 = nw0; w1 = nw1;
    }
    c.u = *(const uint4*)(Bo + n*16 + q*4); bf16x8 ao = c.h;
    f32x4 Z = {0.f,0.f,0.f,0.f};
    return __builtin_amdgcn_mfma_f32_16x16x32_bf16(ao, bb, Z, 0, 0, 0);
}

// ---------------------------------------------------------------------------
// Weight packing (pi layout): dword d of row n = (W[base+d][n], W[base+d+16][n])
// ---------------------------------------------------------------------------
__global__ __launch_bounds__(256) void pack_kernel(
    const float* __restrict__ Win, const float* __restrict__ Wh,
    const float* __restrict__ Wout, u32* __restrict__ dst,
    int din, int dout, int KP)
{
    int t = blockIdx.x * blockDim.x + threadIdx.x;
    int indw = 32*(KP/2);
    int tot = indw + 16384 + 256;
    if (t >= tot) return;
    float lo, hi;
    if (t < indw) {
        int nrow = t / (KP/2), rem = t % (KP/2);
        int T = rem >> 4, d = rem & 15;
        int klo = T*32 + d, khi = klo + 16;
        lo = (klo < din) ? Win[klo*32 + nrow] : 0.f;
        hi = (khi < din) ? Win[khi*32 + nrow] : 0.f;
    } else if (t < indw + 16384) {
        int u = t - indw; int l = u >> 9; int v = u & 511;
        int nrow = v >> 4; int d = v & 15;
        lo = Wh[l*1024 + d*32 + nrow];
        hi = Wh[l*1024 + (d+16)*32 + nrow];
    } else {
        int u = t - indw - 16384; int nrow = u >> 4; int d = u & 15;
        lo = (nrow < dout) ? Wout[d*dout + nrow] : 0.f;
        hi = (nrow < dout) ? Wout[(d+16)*dout + nrow] : 0.f;
    }
    dst[t] = pk2(lo, hi);
}

// ---------------------------------------------------------------------------
// Kernels. Block = 256 thr = 4 waves; each wave owns 16 elements (lane&15).
// No LDS anywhere.
// ---------------------------------------------------------------------------
#define WAVE_SETUP \
    const int lane = threadIdx.x & 63; \
    const int wid  = threadIdx.x >> 6; \
    const int n = lane & 15, q = lane >> 4;

__global__ __launch_bounds__(256, 4) void encode_kernel(
    const float* __restrict__ nodes, const float* __restrict__ edges,
    const float* __restrict__ gvec,
    const int* __restrict__ senders, const int* __restrict__ receivers,
    const u32* __restrict__ Wne, const float* __restrict__ ne_bin,
    const float* __restrict__ ne_bh, const float* __restrict__ ne_bout,
    const u32* __restrict__ Wed, const float* __restrict__ ed_bin,
    const float* __restrict__ ed_bh, const float* __restrict__ ed_bout,
    float* __restrict__ ve, float* __restrict__ ee)
{
    WAVE_SETUP
    const bool edge_stage = blockIdx.x >= 1024;
    const int lb = edge_stage ? (blockIdx.x - 1024) : blockIdx.x;
    const int e0 = (lb*4 + wid) * 16;
    const int e  = e0 + n;        // this lane's element
    const int b  = e >> 15;
    bf16x8 a0;
    {
        uint4 w; w.x = 0u; w.y = 0u; w.z = 0u; w.w = 0u;
        if (!edge_stage) {
            if (q == 0) {
                float2 v01 = *(const float2*)(nodes + (size_t)e*6);
                float2 v23 = *(const float2*)(nodes + (size_t)e*6 + 2);
                w.x = pk2(v01.x, 0.f); w.y = pk2(v01.y, 0.f);
                w.z = pk2(v23.x, 0.f); w.w = pk2(v23.y, 0.f);
            } else if (q == 1) {
                float2 v45 = *(const float2*)(nodes + (size_t)e*6 + 4);
                w.x = pk2(v45.x, 0.f); w.y = pk2(v45.y, 0.f);
                w.z = pk2(gvec[b], 0.f);
            }
        } else {
            if (q < 2) {
                int s = senders[e], r = receivers[e];
                const float* ps = nodes + ((size_t)b*NN + s)*6;
                const float* pr = nodes + ((size_t)b*NN + r)*6;
                float2 s01 = *(const float2*)ps; float s2v = ps[2];
                float2 r01 = *(const float2*)pr; float r2v = pr[2];
                float r0 = s01.x - r01.x, r1 = s01.y - r01.y, r2 = s2v - r2v;
                if (q == 0) {
                    w.x = pk2(edges[e], 0.f); w.y = pk2(r0, 0.f);
                    w.z = pk2(r1, 0.f);       w.w = pk2(r2, 0.f);
                } else {
                    w.x = pk2(sqrtf(r0*r0 + r1*r1 + r2*r2), 0.f);
                }
            }
        }
        U4 c; c.u = w; a0 = c.h;
    }
    const u32*   Wp   = edge_stage ? Wed    : Wne;
    const float* pbin = edge_stage ? ed_bin : ne_bin;
    const float* pbh  = edge_stage ? ed_bh  : ne_bh;
    const float* pbo  = edge_stage ? ed_bout: ne_bout;
    float* dst        = edge_stage ? ee     : ve;
    f32x4 D = mlp_core<1, false>(&a0, Wp, pbin, pbh, pbin, pbin, n, q);
    float4 bo = *(const float4*)(pbo + q*4);
    float4 st;
    st.x = fmaxf(D[0] + bo.x, 0.f); st.y = fmaxf(D[1] + bo.y, 0.f);
    st.z = fmaxf(D[2] + bo.z, 0.f); st.w = fmaxf(D[3] + bo.w, 0.f);
    *(float4*)(dst + (size_t)e*16 + q*4) = st;
}

__global__ __launch_bounds__(256, 4) void edge_update_kernel(
    const float* __restrict__ gvec,
    const int* __restrict__ senders, const int* __restrict__ receivers,
    const float* __restrict__ ve, float* __restrict__ ee, float* __restrict__ agg,
    const u32* __restrict__ Wp, const float* __restrict__ bin,
    const float* __restrict__ bh, const float* __restrict__ bout,
    const float* __restrict__ lng, const float* __restrict__ lnb)
{
    WAVE_SETUP
    const int e0 = (blockIdx.x*4 + wid) * 16;
    const int e  = e0 + n;
    const int b  = e >> 15;
    const int s  = senders[e], r_ = receivers[e];
    // x = [ee(0..15) vs(16..31) vr(32..47) g(48) 0...]
    float4 eev = *(const float4*)(ee + (size_t)e*16 + q*4);
    float4 vsv = *(const float4*)(ve + ((size_t)b*NN + s)*16 + q*4);
    float4 vrv = *(const float4*)(ve + ((size_t)b*NN + r_)*16 + q*4);
    float g = gvec[b];
    bf16x8 a[2];
    {
        U4 c;
        c.u.x = pk2(eev.x, vsv.x); c.u.y = pk2(eev.y, vsv.y);
        c.u.z = pk2(eev.z, vsv.z); c.u.w = pk2(eev.w, vsv.w);
        a[0] = c.h;
        c.u.x = pk2(vrv.x, (q == 0) ? g : 0.f);
        c.u.y = pk2(vrv.y, 0.f);
        c.u.z = pk2(vrv.z, 0.f);
        c.u.w = pk2(vrv.w, 0.f);
        a[1] = c.h;
    }
    f32x4 D = mlp_core<2, true>(a, Wp, bin, bh, lng, lnb, n, q);
    float4 bo = *(const float4*)(bout + q*4);
    float4 st;
    st.x = fmaxf(D[0] + bo.x, 0.f); st.y = fmaxf(D[1] + bo.y, 0.f);
    st.z = fmaxf(D[2] + bo.z, 0.f); st.w = fmaxf(D[3] + bo.w, 0.f);
    *(float4*)(ee + (size_t)e*16 + q*4) = st;
    float* ap = agg + ((size_t)b*NN + r_)*16 + q*4;
    atomicAdd(ap + 0, st.x); atomicAdd(ap + 1, st.y);
    atomicAdd(ap + 2, st.z); atomicAdd(ap + 3, st.w);
}

__global__ __launch_bounds__(256, 4) void node_update_kernel(
    const float* __restrict__ gvec,
    const float* __restrict__ agg, float* __restrict__ ve,
    const u32* __restrict__ Wp, const float* __restrict__ bin,
    const float* __restrict__ bh, const float* __restrict__ bout,
    const float* __restrict__ lng, const float* __restrict__ lnb)
{
    WAVE_SETUP
    const int e0 = (blockIdx.x*4 + wid) * 16;
    const int e  = e0 + n;
    const int b  = e >> 15;
    // x = [agg(0..15) ve(16..31) g(32) 0...]
    float4 agv = *(const float4*)(agg + (size_t)e*16 + q*4);
    float4 vev = *(const float4*)(ve  + (size_t)e*16 + q*4);
    float g = gvec[b];
    bf16x8 a[2];
    {
        U4 c;
        c.u.x = pk2(agv.x, vev.x); c.u.y = pk2(agv.y, vev.y);
        c.u.z = pk2(agv.z, vev.z); c.u.w = pk2(agv.w, vev.w);
        a[0] = c.h;
        c.u.x = (q == 0) ? pk2(g, 0.f) : 0u;
        c.u.y = 0u; c.u.z = 0u; c.u.w = 0u;
        a[1] = c.h;
    }
    f32x4 D = mlp_core<2, true>(a, Wp, bin, bh, lng, lnb, n, q);
    float4 bo = *(const float4*)(bout + q*4);
    float4 st;
    st.x = fmaxf(D[0] + bo.x, 0.f); st.y = fmaxf(D[1] + bo.y, 0.f);
    st.z = fmaxf(D[2] + bo.z, 0.f); st.w = fmaxf(D[3] + bo.w, 0.f);
    *(float4*)(ve + (size_t)e*16 + q*4) = st;
}

__global__ __launch_bounds__(256, 4) void decode_kernel(
    const float* __restrict__ ve,
    const u32* __restrict__ Wp, const float* __restrict__ bin,
    const float* __restrict__ bh, const float* __restrict__ bout,
    float* __restrict__ out)
{
    WAVE_SETUP
    const int e0 = (blockIdx.x*4 + wid) * 16;
    const int e  = e0 + n;
    float4 vev = *(const float4*)(ve + (size_t)e*16 + q*4);
    bf16x8 a0;
    {
        U4 c;
        c.u.x = pk2(vev.x, 0.f); c.u.y = pk2(vev.y, 0.f);
        c.u.z = pk2(vev.z, 0.f); c.u.w = pk2(vev.w, 0.f);
        a0 = c.h;
    }
    f32x4 D = mlp_core<1, false>(&a0, Wp, bin, bh, bin, bin, n, q);
    // out-features q*4+r of element e; only feats 0..2 exist -> q==0, r<3
    if (q == 0) {
        out[(size_t)e*3 + 0] = fmaxf(D[0] + bout[0], 0.f);
        out[(size_t)e*3 + 1] = fmaxf(D[1] + bout[1], 0.f);
        out[(size_t)e*3 + 2] = fmaxf(D[2] + bout[2], 0.f);
    }
}

// ---------------------------------------------------------------------------
// launch
// ---------------------------------------------------------------------------
extern "C" void kernel_launch(void* const* d_in, const int* in_sizes, int n_in,
                              void* d_out, int out_size, void* d_ws, size_t ws_size,
                              hipStream_t stream)
{
    const float* nodes     = (const float*)d_in[0];
    const float* edges     = (const float*)d_in[1];
    const float* gvec      = (const float*)d_in[2];
    const int*   senders   = (const int*)  d_in[3];
    const int*   receivers = (const int*)  d_in[4];

    const float* ne_Win  = (const float*)d_in[5];
    const float* ne_bin  = (const float*)d_in[6];
    const float* ne_Wh   = (const float*)d_in[7];
    const float* ne_bh   = (const float*)d_in[8];
    const float* ne_Wout = (const float*)d_in[9];
    const float* ne_bout = (const float*)d_in[10];

    const float* ed_Win  = (const float*)d_in[11];
    const float* ed_bin  = (const float*)d_in[12];
    const float* ed_Wh   = (const float*)d_in[13];
    const float* ed_bh   = (const float*)d_in[14];
    const float* ed_Wout = (const float*)d_in[15];
    const float* ed_bout = (const float*)d_in[16];

    const float* pe_Win  = (const float*)d_in[17];
    const float* pe_bin  = (const float*)d_in[18];
    const float* pe_Wh   = (const float*)d_in[19];
    const float* pe_bh   = (const float*)d_in[20];
    const float* pe_Wout = (const float*)d_in[21];
    const float* pe_bout = (const float*)d_in[22];
    const float* pe_lng  = (const float*)d_in[23];
    const float* pe_lnb  = (const float*)d_in[24];

    const float* pv_Win  = (const float*)d_in[25];
    const float* pv_bin  = (const float*)d_in[26];
    const float* pv_Wh   = (const float*)d_in[27];
    const float* pv_bh   = (const float*)d_in[28];
    const float* pv_Wout = (const float*)d_in[29];
    const float* pv_bout = (const float*)d_in[30];
    const float* pv_lng  = (const float*)d_in[31];
    const float* pv_lnb  = (const float*)d_in[32];

    const float* de_Win  = (const float*)d_in[33];
    const float* de_bin  = (const float*)d_in[34];
    const float* de_Wh   = (const float*)d_in[35];
    const float* de_bh   = (const float*)d_in[36];
    const float* de_Wout = (const float*)d_in[37];
    const float* de_bout = (const float*)d_in[38];

    // workspace: ve | ee | agg (4 MB each) | packed bf16 weights
    float* ve  = (float*)d_ws;
    float* ee  = ve + (size_t)1048576;
    float* agg = ee + (size_t)1048576;
    u32* Wne = (u32*)(agg + (size_t)1048576);
    u32* Wed = Wne + 17152;
    u32* Wpe = Wed + 17152;
    u32* Wpv = Wpe + 17664;
    u32* Wde = Wpv + 17664;

    const dim3 blk(256);

    pack_kernel<<<70, blk, 0, stream>>>(ne_Win, ne_Wh, ne_Wout, Wne,  7, 16, 32);
    pack_kernel<<<70, blk, 0, stream>>>(ed_Win, ed_Wh, ed_Wout, Wed,  5, 16, 32);
    pack_kernel<<<70, blk, 0, stream>>>(pe_Win, pe_Wh, pe_Wout, Wpe, 49, 16, 64);
    pack_kernel<<<70, blk, 0, stream>>>(pv_Win, pv_Wh, pv_Wout, Wpv, 33, 16, 64);
    pack_kernel<<<70, blk, 0, stream>>>(de_Win, de_Wh, de_Wout, Wde, 16,  3, 32);

    encode_kernel<<<2048, blk, 0, stream>>>(nodes, edges, gvec, senders, receivers,
        Wne, ne_bin, ne_bh, ne_bout,
        Wed, ed_bin, ed_bh, ed_bout, ve, ee);

    for (int step = 0; step < 2; ++step) {
        hipMemsetAsync(agg, 0, (size_t)BB * NN * 16 * sizeof(float), stream);
        edge_update_kernel<<<1024, blk, 0, stream>>>(gvec, senders, receivers,
            ve, ee, agg, Wpe, pe_bin, pe_bh, pe_bout, pe_lng, pe_lnb);
        node_update_kernel<<<1024, blk, 0, stream>>>(gvec, agg, ve,
            Wpv, pv_bin, pv_bh, pv_bout, pv_lng, pv_lnb);
    }

    decode_kernel<<<1024, blk, 0, stream>>>(ve,
        Wde, de_bin, de_bh, de_bout, (float*)d_out);
}

// Round 7
// 342.207 us; speedup vs baseline: 1.1951x; 1.1951x over previous
//
#include <hip/hip_runtime.h>

#define BB 2
#define NN 32768
#define EN 32768

typedef unsigned int u32;
typedef __attribute__((ext_vector_type(8))) short bf16x8;
typedef __attribute__((ext_vector_type(4))) float f32x4;

union U4 { uint4 u; bf16x8 h; };

// ---------------------------------------------------------------------------
// f32 pair -> packed bf16 dword (RNE). HW instr on gfx950 when available.
// ---------------------------------------------------------------------------
#if defined(__has_builtin)
#if __has_builtin(__builtin_amdgcn_cvt_pk_bf16_f32)
#define HAVE_CVT_PK 1
#endif
#endif

#ifdef HAVE_CVT_PK
typedef __attribute__((ext_vector_type(2))) __bf16 bfv2;
__device__ __forceinline__ u32 pk2(float lo, float hi) {
    bfv2 v = __builtin_amdgcn_cvt_pk_bf16_f32(lo, hi);
    return __builtin_bit_cast(u32, v);
}
#else
__device__ __forceinline__ u32 pk2(float lo, float hi) {
    u32 a = __builtin_bit_cast(u32, lo);
    u32 b = __builtin_bit_cast(u32, hi);
    a += 0x7FFFu + ((a >> 16) & 1u);
    b += 0x7FFFu + ((b >> 16) & 1u);
    return (a >> 16) | (b & 0xFFFF0000u);
}
#endif

// ---------------------------------------------------------------------------
// Layer epilogue (register-resident, LN affine pre-folded into weights).
// Weights = MFMA A-operand (m = out-feature), activations = B-operand
// (n = element). Lane (n,q) holds out-features q*4+r (D0) and 16+q*4+r (D1)
// of element n. Under the pi k-permutation the packed dword i =
// pk2(y_lo[i], y_hi[i]) IS the next layer's B-frag dword i.
// LN here is normalize-only: (y - mu) * rsqrt(var + eps); gamma/beta live in
// the packed weights / folded biases (pack-time transform).
// ---------------------------------------------------------------------------
template<bool LN>
__device__ __forceinline__ bf16x8 transform(
    f32x4 D0, f32x4 D1, const float* __restrict__ bias, int q)
{
    float4 bl = *(const float4*)(bias + q*4);
    float4 bh = *(const float4*)(bias + q*4 + 16);
    float y0 = fmaxf(D0[0] + bl.x, 0.f), y1 = fmaxf(D0[1] + bl.y, 0.f);
    float y2 = fmaxf(D0[2] + bl.z, 0.f), y3 = fmaxf(D0[3] + bl.w, 0.f);
    float z0 = fmaxf(D1[0] + bh.x, 0.f), z1 = fmaxf(D1[1] + bh.y, 0.f);
    float z2 = fmaxf(D1[2] + bh.z, 0.f), z3 = fmaxf(D1[3] + bh.w, 0.f);
    if (LN) {
        float s = ((y0+y1)+(y2+y3)) + ((z0+z1)+(z2+z3));
        float s2 = 0.f;
        s2 = fmaf(y0,y0,s2); s2 = fmaf(y1,y1,s2); s2 = fmaf(y2,y2,s2); s2 = fmaf(y3,y3,s2);
        s2 = fmaf(z0,z0,s2); s2 = fmaf(z1,z1,s2); s2 = fmaf(z2,z2,s2); s2 = fmaf(z3,z3,s2);
        s  += __shfl_xor(s, 16);  s  += __shfl_xor(s, 32);
        s2 += __shfl_xor(s2, 16); s2 += __shfl_xor(s2, 32);
        float mu  = s * (1.f/32.f);
        float var = fmaf(-mu, mu, s2 * (1.f/32.f));
        float rs  = rsqrtf(var + 1e-5f);
        float nt  = -mu * rs;
        y0 = fmaf(y0, rs, nt); y1 = fmaf(y1, rs, nt);
        y2 = fmaf(y2, rs, nt); y3 = fmaf(y3, rs, nt);
        z0 = fmaf(z0, rs, nt); z1 = fmaf(z1, rs, nt);
        z2 = fmaf(z2, rs, nt); z3 = fmaf(z3, rs, nt);
    }
    U4 c;
    c.u.x = pk2(y0, z0); c.u.y = pk2(y1, z1);
    c.u.z = pk2(y2, z2); c.u.w = pk2(y3, z3);
    return c.h;
}

// ---------------------------------------------------------------------------
// Wave-level deep MLP, register-resident between layers.
// Wp (pi layout): [Bin 32 x KT*16 dw] [Bh 32 x 32 x 16 dw] [Bo 16 x 16 dw]
// bin = input-layer bias (32); bhid = per-hidden-layer biases (32x32;
// LN-folded for LN MLPs). Returns final MFMA D (pre-bias).
// ---------------------------------------------------------------------------
template<int KT, bool LN>
__device__ __forceinline__ f32x4 mlp_core(
    const bf16x8* b_in, const u32* __restrict__ Wp,
    const float* __restrict__ bin, const float* __restrict__ bhid,
    int n, int q)
{
    const u32* Bh = Wp + 32*KT*16;
    const u32* Bo = Bh + 16384;
    U4 c;
    f32x4 D0 = {0.f,0.f,0.f,0.f}, D1 = {0.f,0.f,0.f,0.f};
    #pragma unroll
    for (int T = 0; T < KT; ++T) {
        c.u = *(const uint4*)(Wp + (size_t)n*(KT*16) + T*16 + q*4);      bf16x8 a0 = c.h;
        c.u = *(const uint4*)(Wp + (size_t)(n+16)*(KT*16) + T*16 + q*4); bf16x8 a1 = c.h;
        D0 = __builtin_amdgcn_mfma_f32_16x16x32_bf16(a0, b_in[T], D0, 0, 0, 0);
        D1 = __builtin_amdgcn_mfma_f32_16x16x32_bf16(a1, b_in[T], D1, 0, 0, 0);
    }
    // prefetch layer-0 weights before the input epilogue
    c.u = *(const uint4*)(Bh + n*16 + q*4);       bf16x8 w0 = c.h;
    c.u = *(const uint4*)(Bh + (n+16)*16 + q*4);  bf16x8 w1 = c.h;
    bf16x8 bb = transform<LN>(D0, D1, bin, q);
    #pragma unroll 1
    for (int l = 0; l < 32; ++l) {
        const int lnx = (l+1 < 32) ? l+1 : 31;
        const u32* Bn = Bh + lnx*512;
        c.u = *(const uint4*)(Bn + n*16 + q*4);       bf16x8 nw0 = c.h;
        c.u = *(const uint4*)(Bn + (n+16)*16 + q*4);  bf16x8 nw1 = c.h;
        f32x4 Z = {0.f,0.f,0.f,0.f};
        f32x4 E0 = __builtin_amdgcn_mfma_f32_16x16x32_bf16(w0, bb, Z, 0, 0, 0);
        f32x4 E1 = __builtin_amdgcn_mfma_f32_16x16x32_bf16(w1, bb, Z, 0, 0, 0);
        bb = transform<LN>(E0, E1, bhid + l*32, q);
        w0 = nw0; w1 = nw1;
    }
    c.u = *(const uint4*)(Bo + n*16 + q*4); bf16x8 ao = c.h;
    f32x4 Z = {0.f,0.f,0.f,0.f};
    return __builtin_amdgcn_mfma_f32_16x16x32_bf16(ao, bb, Z, 0, 0, 0);
}

// ---------------------------------------------------------------------------
// Weight packing (pi layout): dword d of row n = (W[base+d][n], W[base+d+16][n])
// If lng != nullptr, the preceding LayerNorm's gamma is folded in:
// hidden layer l consumes LN[l]; the output layer consumes LN[32].
// ---------------------------------------------------------------------------
__global__ __launch_bounds__(256) void pack_kernel(
    const float* __restrict__ Win, const float* __restrict__ Wh,
    const float* __restrict__ Wout, const float* __restrict__ lng,
    u32* __restrict__ dst, int din, int dout, int KP)
{
    int t = blockIdx.x * blockDim.x + threadIdx.x;
    int indw = 32*(KP/2);
    int tot = indw + 16384 + 256;
    if (t >= tot) return;
    float lo, hi;
    if (t < indw) {
        int nrow = t / (KP/2), rem = t % (KP/2);
        int T = rem >> 4, d = rem & 15;
        int klo = T*32 + d, khi = klo + 16;
        lo = (klo < din) ? Win[klo*32 + nrow] : 0.f;
        hi = (khi < din) ? Win[khi*32 + nrow] : 0.f;
    } else if (t < indw + 16384) {
        int u = t - indw; int l = u >> 9; int v = u & 511;
        int nrow = v >> 4; int d = v & 15;
        lo = Wh[l*1024 + d*32 + nrow];
        hi = Wh[l*1024 + (d+16)*32 + nrow];
        if (lng) { lo *= lng[l*32 + d]; hi *= lng[l*32 + d + 16]; }
    } else {
        int u = t - indw - 16384; int nrow = u >> 4; int d = u & 15;
        lo = (nrow < dout) ? Wout[d*dout + nrow] : 0.f;
        hi = (nrow < dout) ? Wout[(d+16)*dout + nrow] : 0.f;
        if (lng) { lo *= lng[1024 + d]; hi *= lng[1024 + d + 16]; }
    }
    dst[t] = pk2(lo, hi);
}

// ---------------------------------------------------------------------------
// Fold LN beta into the next matmul's bias:
//   fb[l][j]    = bh[l][j]  + sum_k lnb[l][k]  * Wh[l][k][j]   (j<32, l<32)
//   fb[1024+j]  = bout[j]   + sum_k lnb[32][k] * Wout[k][j]    (j<16)
// ---------------------------------------------------------------------------
__global__ __launch_bounds__(256) void fold_bias_kernel(
    const float* __restrict__ Wh,   const float* __restrict__ bh,
    const float* __restrict__ Wout, const float* __restrict__ bout,
    const float* __restrict__ lnb,  float* __restrict__ fb)
{
    int j = blockIdx.x * blockDim.x + threadIdx.x;
    if (j < 1024) {
        int l = j >> 5, jj = j & 31;
        float acc = bh[j];
        #pragma unroll
        for (int k = 0; k < 32; ++k)
            acc = fmaf(lnb[l*32 + k], Wh[l*1024 + k*32 + jj], acc);
        fb[j] = acc;
    } else if (j < 1024 + 16) {
        int jj = j - 1024;
        float acc = bout[jj];
        #pragma unroll
        for (int k = 0; k < 32; ++k)
            acc = fmaf(lnb[1024 + k], Wout[k*16 + jj], acc);
        fb[j] = acc;
    }
}

// ---------------------------------------------------------------------------
// Kernels. Block = 256 thr = 4 waves; each wave owns 16 elements (lane&15).
// ---------------------------------------------------------------------------
#define WAVE_SETUP \
    const int lane = threadIdx.x & 63; \
    const int wid  = threadIdx.x >> 6; \
    const int n = lane & 15, q = lane >> 4;

__global__ __launch_bounds__(256, 4) void encode_kernel(
    const float* __restrict__ nodes, const float* __restrict__ edges,
    const float* __restrict__ gvec,
    const int* __restrict__ senders, const int* __restrict__ receivers,
    const u32* __restrict__ Wne, const float* __restrict__ ne_bin,
    const float* __restrict__ ne_bh, const float* __restrict__ ne_bout,
    const u32* __restrict__ Wed, const float* __restrict__ ed_bin,
    const float* __restrict__ ed_bh, const float* __restrict__ ed_bout,
    float* __restrict__ ve, float* __restrict__ ee)
{
    WAVE_SETUP
    const bool edge_stage = blockIdx.x >= 1024;
    const int lb = edge_stage ? (blockIdx.x - 1024) : blockIdx.x;
    const int e0 = (lb*4 + wid) * 16;
    const int e  = e0 + n;        // this lane's element
    const int b  = e >> 15;
    bf16x8 a0;
    {
        uint4 w; w.x = 0u; w.y = 0u; w.z = 0u; w.w = 0u;
        if (!edge_stage) {
            if (q == 0) {
                float2 v01 = *(const float2*)(nodes + (size_t)e*6);
                float2 v23 = *(const float2*)(nodes + (size_t)e*6 + 2);
                w.x = pk2(v01.x, 0.f); w.y = pk2(v01.y, 0.f);
                w.z = pk2(v23.x, 0.f); w.w = pk2(v23.y, 0.f);
            } else if (q == 1) {
                float2 v45 = *(const float2*)(nodes + (size_t)e*6 + 4);
                w.x = pk2(v45.x, 0.f); w.y = pk2(v45.y, 0.f);
                w.z = pk2(gvec[b], 0.f);
            }
        } else {
            if (q < 2) {
                int s = senders[e], r = receivers[e];
                const float* ps = nodes + ((size_t)b*NN + s)*6;
                const float* pr = nodes + ((size_t)b*NN + r)*6;
                float2 s01 = *(const float2*)ps; float s2v = ps[2];
                float2 r01 = *(const float2*)pr; float r2v = pr[2];
                float r0 = s01.x - r01.x, r1 = s01.y - r01.y, r2 = s2v - r2v;
                if (q == 0) {
                    w.x = pk2(edges[e], 0.f); w.y = pk2(r0, 0.f);
                    w.z = pk2(r1, 0.f);       w.w = pk2(r2, 0.f);
                } else {
                    w.x = pk2(sqrtf(r0*r0 + r1*r1 + r2*r2), 0.f);
                }
            }
        }
        U4 c; c.u = w; a0 = c.h;
    }
    const u32*   Wp   = edge_stage ? Wed    : Wne;
    const float* pbin = edge_stage ? ed_bin : ne_bin;
    const float* pbh  = edge_stage ? ed_bh  : ne_bh;
    const float* pbo  = edge_stage ? ed_bout: ne_bout;
    float* dst        = edge_stage ? ee     : ve;
    f32x4 D = mlp_core<1, false>(&a0, Wp, pbin, pbh, n, q);
    float4 bo = *(const float4*)(pbo + q*4);
    float4 st;
    st.x = fmaxf(D[0] + bo.x, 0.f); st.y = fmaxf(D[1] + bo.y, 0.f);
    st.z = fmaxf(D[2] + bo.z, 0.f); st.w = fmaxf(D[3] + bo.w, 0.f);
    *(float4*)(dst + (size_t)e*16 + q*4) = st;
}

__global__ __launch_bounds__(256, 4) void edge_update_kernel(
    const float* __restrict__ gvec,
    const int* __restrict__ senders, const int* __restrict__ receivers,
    const float* __restrict__ ve, float* __restrict__ ee, float* __restrict__ agg,
    const u32* __restrict__ Wp, const float* __restrict__ bin,
    const float* __restrict__ fb)
{
    __shared__ __align__(16) float Xs[4*320];
    WAVE_SETUP
    float* X = Xs + wid*320;
    const int e0 = (blockIdx.x*4 + wid) * 16;
    const int e  = e0 + n;
    const int b  = e >> 15;
    const int s  = senders[e], r_ = receivers[e];
    // x = [ee(0..15) vs(16..31) vr(32..47) g(48) 0...]
    float4 eev = *(const float4*)(ee + (size_t)e*16 + q*4);
    float4 vsv = *(const float4*)(ve + ((size_t)b*NN + s)*16 + q*4);
    float4 vrv = *(const float4*)(ve + ((size_t)b*NN + r_)*16 + q*4);
    float g = gvec[b];
    bf16x8 a[2];
    {
        U4 c;
        c.u.x = pk2(eev.x, vsv.x); c.u.y = pk2(eev.y, vsv.y);
        c.u.z = pk2(eev.z, vsv.z); c.u.w = pk2(eev.w, vsv.w);
        a[0] = c.h;
        c.u.x = pk2(vrv.x, (q == 0) ? g : 0.f);
        c.u.y = pk2(vrv.y, 0.f);
        c.u.z = pk2(vrv.z, 0.f);
        c.u.w = pk2(vrv.w, 0.f);
        a[1] = c.h;
    }
    f32x4 D = mlp_core<2, true>(a, Wp, bin, fb, n, q);
    float4 bo = *(const float4*)(fb + 1024 + q*4);
    float4 st;
    st.x = fmaxf(D[0] + bo.x, 0.f); st.y = fmaxf(D[1] + bo.y, 0.f);
    st.z = fmaxf(D[2] + bo.z, 0.f); st.w = fmaxf(D[3] + bo.w, 0.f);
    *(float4*)(ee + (size_t)e*16 + q*4) = st;
    // Transpose once through wave-private LDS so each atomic instruction
    // hits 4 receiver lines (16 lanes sharing a receiver), not 16.
    *(float4*)(X + n*20 + q*4) = st;
    #pragma unroll
    for (int rr = 0; rr < 4; ++rr) {
        int em = e0 + q*4 + rr;
        float v = X[(q*4+rr)*20 + n];
        int rc = __shfl(r_, q*4 + rr);
        atomicAdd(agg + ((size_t)(em >> 15)*NN + rc)*16 + n, v);
    }
}

__global__ __launch_bounds__(256, 4) void node_update_kernel(
    const float* __restrict__ gvec,
    const float* __restrict__ agg, float* __restrict__ ve,
    const u32* __restrict__ Wp, const float* __restrict__ bin,
    const float* __restrict__ fb)
{
    WAVE_SETUP
    const int e0 = (blockIdx.x*4 + wid) * 16;
    const int e  = e0 + n;
    const int b  = e >> 15;
    // x = [agg(0..15) ve(16..31) g(32) 0...]
    float4 agv = *(const float4*)(agg + (size_t)e*16 + q*4);
    float4 vev = *(const float4*)(ve  + (size_t)e*16 + q*4);
    float g = gvec[b];
    bf16x8 a[2];
    {
        U4 c;
        c.u.x = pk2(agv.x, vev.x); c.u.y = pk2(agv.y, vev.y);
        c.u.z = pk2(agv.z, vev.z); c.u.w = pk2(agv.w, vev.w);
        a[0] = c.h;
        c.u.x = (q == 0) ? pk2(g, 0.f) : 0u;
        c.u.y = 0u; c.u.z = 0u; c.u.w = 0u;
        a[1] = c.h;
    }
    f32x4 D = mlp_core<2, true>(a, Wp, bin, fb, n, q);
    float4 bo = *(const float4*)(fb + 1024 + q*4);
    float4 st;
    st.x = fmaxf(D[0] + bo.x, 0.f); st.y = fmaxf(D[1] + bo.y, 0.f);
    st.z = fmaxf(D[2] + bo.z, 0.f); st.w = fmaxf(D[3] + bo.w, 0.f);
    *(float4*)(ve + (size_t)e*16 + q*4) = st;
}

__global__ __launch_bounds__(256, 4) void decode_kernel(
    const float* __restrict__ ve,
    const u32* __restrict__ Wp, const float* __restrict__ bin,
    const float* __restrict__ bh, const float* __restrict__ bout,
    float* __restrict__ out)
{
    WAVE_SETUP
    const int e0 = (blockIdx.x*4 + wid) * 16;
    const int e  = e0 + n;
    float4 vev = *(const float4*)(ve + (size_t)e*16 + q*4);
    bf16x8 a0;
    {
        U4 c;
        c.u.x = pk2(vev.x, 0.f); c.u.y = pk2(vev.y, 0.f);
        c.u.z = pk2(vev.z, 0.f); c.u.w = pk2(vev.w, 0.f);
        a0 = c.h;
    }
    f32x4 D = mlp_core<1, false>(&a0, Wp, bin, bh, n, q);
    // out-features q*4+r of element e; only feats 0..2 exist -> q==0, r<3
    if (q == 0) {
        out[(size_t)e*3 + 0] = fmaxf(D[0] + bout[0], 0.f);
        out[(size_t)e*3 + 1] = fmaxf(D[1] + bout[1], 0.f);
        out[(size_t)e*3 + 2] = fmaxf(D[2] + bout[2], 0.f);
    }
}

// ---------------------------------------------------------------------------
// launch
// ---------------------------------------------------------------------------
extern "C" void kernel_launch(void* const* d_in, const int* in_sizes, int n_in,
                              void* d_out, int out_size, void* d_ws, size_t ws_size,
                              hipStream_t stream)
{
    const float* nodes     = (const float*)d_in[0];
    const float* edges     = (const float*)d_in[1];
    const float* gvec      = (const float*)d_in[2];
    const int*   senders   = (const int*)  d_in[3];
    const int*   receivers = (const int*)  d_in[4];

    const float* ne_Win  = (const float*)d_in[5];
    const float* ne_bin  = (const float*)d_in[6];
    const float* ne_Wh   = (const float*)d_in[7];
    const float* ne_bh   = (const float*)d_in[8];
    const float* ne_Wout = (const float*)d_in[9];
    const float* ne_bout = (const float*)d_in[10];

    const float* ed_Win  = (const float*)d_in[11];
    const float* ed_bin  = (const float*)d_in[12];
    const float* ed_Wh   = (const float*)d_in[13];
    const float* ed_bh   = (const float*)d_in[14];
    const float* ed_Wout = (const float*)d_in[15];
    const float* ed_bout = (const float*)d_in[16];

    const float* pe_Win  = (const float*)d_in[17];
    const float* pe_bin  = (const float*)d_in[18];
    const float* pe_Wh   = (const float*)d_in[19];
    const float* pe_bh   = (const float*)d_in[20];
    const float* pe_Wout = (const float*)d_in[21];
    const float* pe_bout = (const float*)d_in[22];
    const float* pe_lng  = (const float*)d_in[23];
    const float* pe_lnb  = (const float*)d_in[24];

    const float* pv_Win  = (const float*)d_in[25];
    const float* pv_bin  = (const float*)d_in[26];
    const float* pv_Wh   = (const float*)d_in[27];
    const float* pv_bh   = (const float*)d_in[28];
    const float* pv_Wout = (const float*)d_in[29];
    const float* pv_bout = (const float*)d_in[30];
    const float* pv_lng  = (const float*)d_in[31];
    const float* pv_lnb  = (const float*)d_in[32];

    const float* de_Win  = (const float*)d_in[33];
    const float* de_bin  = (const float*)d_in[34];
    const float* de_Wh   = (const float*)d_in[35];
    const float* de_bh   = (const float*)d_in[36];
    const float* de_Wout = (const float*)d_in[37];
    const float* de_bout = (const float*)d_in[38];

    // workspace: ve | ee | agg (4 MB each) | packed bf16 weights | folded biases
    float* ve  = (float*)d_ws;
    float* ee  = ve + (size_t)1048576;
    float* agg = ee + (size_t)1048576;
    u32* Wne = (u32*)(agg + (size_t)1048576);
    u32* Wed = Wne + 17152;
    u32* Wpe = Wed + 17152;
    u32* Wpv = Wpe + 17664;
    u32* Wde = Wpv + 17664;
    float* Fpe = (float*)(Wde + 17152);
    float* Fpv = Fpe + 1040;

    const dim3 blk(256);

    pack_kernel<<<70, blk, 0, stream>>>(ne_Win, ne_Wh, ne_Wout, nullptr, Wne,  7, 16, 32);
    pack_kernel<<<70, blk, 0, stream>>>(ed_Win, ed_Wh, ed_Wout, nullptr, Wed,  5, 16, 32);
    pack_kernel<<<70, blk, 0, stream>>>(pe_Win, pe_Wh, pe_Wout, pe_lng,  Wpe, 49, 16, 64);
    pack_kernel<<<70, blk, 0, stream>>>(pv_Win, pv_Wh, pv_Wout, pv_lng,  Wpv, 33, 16, 64);
    pack_kernel<<<70, blk, 0, stream>>>(de_Win, de_Wh, de_Wout, nullptr, Wde, 16,  3, 32);
    fold_bias_kernel<<<5, blk, 0, stream>>>(pe_Wh, pe_bh, pe_Wout, pe_bout, pe_lnb, Fpe);
    fold_bias_kernel<<<5, blk, 0, stream>>>(pv_Wh, pv_bh, pv_Wout, pv_bout, pv_lnb, Fpv);

    encode_kernel<<<2048, blk, 0, stream>>>(nodes, edges, gvec, senders, receivers,
        Wne, ne_bin, ne_bh, ne_bout,
        Wed, ed_bin, ed_bh, ed_bout, ve, ee);

    for (int step = 0; step < 2; ++step) {
        hipMemsetAsync(agg, 0, (size_t)BB * NN * 16 * sizeof(float), stream);
        edge_update_kernel<<<1024, blk, 0, stream>>>(gvec, senders, receivers,
            ve, ee, agg, Wpe, pe_bin, Fpe);
        node_update_kernel<<<1024, blk, 0, stream>>>(gvec, agg, ve,
            Wpv, pv_bin, Fpv);
    }

    decode_kernel<<<1024, blk, 0, stream>>>(ve,
        Wde, de_bin, de_bh, de_bout, (float*)d_out);
}

// Round 8
// 325.741 us; speedup vs baseline: 1.2555x; 1.0505x over previous
//
#include <hip/hip_runtime.h>

#define BB 2
#define NN 32768
#define EN 32768

typedef unsigned int u32;
typedef __attribute__((ext_vector_type(8))) short bf16x8;
typedef __attribute__((ext_vector_type(4))) float f32x4;

union U4 { uint4 u; bf16x8 h; };

// ---------------------------------------------------------------------------
// f32 pair -> packed bf16 dword (RNE). HW instr on gfx950 when available.
// ---------------------------------------------------------------------------
#if defined(__has_builtin)
#if __has_builtin(__builtin_amdgcn_cvt_pk_bf16_f32)
#define HAVE_CVT_PK 1
#endif
#endif

#ifdef HAVE_CVT_PK
typedef __attribute__((ext_vector_type(2))) __bf16 bfv2;
__device__ __forceinline__ u32 pk2(float lo, float hi) {
    bfv2 v = __builtin_amdgcn_cvt_pk_bf16_f32(lo, hi);
    return __builtin_bit_cast(u32, v);
}
#else
__device__ __forceinline__ u32 pk2(float lo, float hi) {
    u32 a = __builtin_bit_cast(u32, lo);
    u32 b = __builtin_bit_cast(u32, hi);
    a += 0x7FFFu + ((a >> 16) & 1u);
    b += 0x7FFFu + ((b >> 16) & 1u);
    return (a >> 16) | (b & 0xFFFF0000u);
}
#endif

__device__ __forceinline__ f32x4 MF(bf16x8 a, bf16x8 b, f32x4 c) {
    return __builtin_amdgcn_mfma_f32_16x16x32_bf16(a, b, c, 0, 0, 0);
}

// ---------------------------------------------------------------------------
// Layer epilogue (register-resident; LN affine pre-folded into weights).
// Weights = A-operand (m = out-feature), activations = B-operand (n = elem).
// Lane (n,q): out-feats q*4+r (D0) / 16+q*4+r (D1) of element n. Under the
// pi k-permutation pk2(y_lo[i], y_hi[i]) IS the next layer's B-frag dword i.
// LN = normalize-only; bias values passed in registers (shared by groups).
// ---------------------------------------------------------------------------
template<bool LN>
__device__ __forceinline__ bf16x8 transform(f32x4 D0, f32x4 D1,
                                            float4 bl, float4 bh)
{
    float y0 = fmaxf(D0[0] + bl.x, 0.f), y1 = fmaxf(D0[1] + bl.y, 0.f);
    float y2 = fmaxf(D0[2] + bl.z, 0.f), y3 = fmaxf(D0[3] + bl.w, 0.f);
    float z0 = fmaxf(D1[0] + bh.x, 0.f), z1 = fmaxf(D1[1] + bh.y, 0.f);
    float z2 = fmaxf(D1[2] + bh.z, 0.f), z3 = fmaxf(D1[3] + bh.w, 0.f);
    if (LN) {
        float s = ((y0+y1)+(y2+y3)) + ((z0+z1)+(z2+z3));
        float s2 = 0.f;
        s2 = fmaf(y0,y0,s2); s2 = fmaf(y1,y1,s2); s2 = fmaf(y2,y2,s2); s2 = fmaf(y3,y3,s2);
        s2 = fmaf(z0,z0,s2); s2 = fmaf(z1,z1,s2); s2 = fmaf(z2,z2,s2); s2 = fmaf(z3,z3,s2);
        s  += __shfl_xor(s, 16);  s  += __shfl_xor(s, 32);
        s2 += __shfl_xor(s2, 16); s2 += __shfl_xor(s2, 32);
        float mu  = s * (1.f/32.f);
        float var = fmaf(-mu, mu, s2 * (1.f/32.f));
        float rs  = rsqrtf(var + 1e-5f);
        float nt  = -mu * rs;
        y0 = fmaf(y0, rs, nt); y1 = fmaf(y1, rs, nt);
        y2 = fmaf(y2, rs, nt); y3 = fmaf(y3, rs, nt);
        z0 = fmaf(z0, rs, nt); z1 = fmaf(z1, rs, nt);
        z2 = fmaf(z2, rs, nt); z3 = fmaf(z3, rs, nt);
    }
    U4 c;
    c.u.x = pk2(y0, z0); c.u.y = pk2(y1, z1);
    c.u.z = pk2(y2, z2); c.u.w = pk2(y3, z3);
    return c.h;
}

// ---------------------------------------------------------------------------
// Wave-level deep MLP over TWO independent 16-element groups (A, B).
// The two groups' MFMA->transform chains interleave -> 2x ILP hides MFMA
// latency and weight-load latency; weights amortized over 32 elements.
// Depth-2 register prefetch of next layers' weights covers L2 (~300 cyc).
// Wp (pi layout): [Bin 32 x KT*16 dw] [Bh 32 x 512 dw] [Bo 256 dw]
// ---------------------------------------------------------------------------
template<int KT, bool LN>
__device__ __forceinline__ void mlp_core2(
    const bf16x8* bA, const bf16x8* bB, const u32* __restrict__ Wp,
    const float* __restrict__ bin, const float* __restrict__ bhid,
    int n, int q, f32x4& OA, f32x4& OB)
{
    const u32* Bh = Wp + 32*KT*16;
    const u32* Bo = Bh + 16384;
    U4 c;
    const f32x4 Z = {0.f,0.f,0.f,0.f};
    f32x4 A0 = Z, A1 = Z, B0 = Z, B1 = Z;
    #pragma unroll
    for (int T = 0; T < KT; ++T) {
        c.u = *(const uint4*)(Wp + (size_t)n*(KT*16) + T*16 + q*4);      bf16x8 a0 = c.h;
        c.u = *(const uint4*)(Wp + (size_t)(n+16)*(KT*16) + T*16 + q*4); bf16x8 a1 = c.h;
        A0 = MF(a0, bA[T], A0); A1 = MF(a1, bA[T], A1);
        B0 = MF(a0, bB[T], B0); B1 = MF(a1, bB[T], B1);
    }
    // prefetch layer 0 and layer 1 weights
    c.u = *(const uint4*)(Bh + n*16 + q*4);            bf16x8 w0 = c.h;
    c.u = *(const uint4*)(Bh + (n+16)*16 + q*4);       bf16x8 w1 = c.h;
    c.u = *(const uint4*)(Bh + 512 + n*16 + q*4);      bf16x8 x0 = c.h;
    c.u = *(const uint4*)(Bh + 512 + (n+16)*16 + q*4); bf16x8 x1 = c.h;
    float4 bl = *(const float4*)(bin + q*4);
    float4 bh = *(const float4*)(bin + q*4 + 16);
    bf16x8 bb0 = transform<LN>(A0, A1, bl, bh);
    bf16x8 bb1 = transform<LN>(B0, B1, bl, bh);
    #pragma unroll 1
    for (int l = 0; l < 32; ++l) {
        const int lp = (l+2 < 32) ? l+2 : 31;
        const u32* Bn = Bh + lp*512;
        c.u = *(const uint4*)(Bn + n*16 + q*4);       bf16x8 nw0 = c.h;
        c.u = *(const uint4*)(Bn + (n+16)*16 + q*4);  bf16x8 nw1 = c.h;
        bl = *(const float4*)(bhid + l*32 + q*4);
        bh = *(const float4*)(bhid + l*32 + q*4 + 16);
        f32x4 E0 = MF(w0, bb0, Z);
        f32x4 E1 = MF(w1, bb0, Z);
        f32x4 F0 = MF(w0, bb1, Z);
        f32x4 F1 = MF(w1, bb1, Z);
        bb0 = transform<LN>(E0, E1, bl, bh);
        bb1 = transform<LN>(F0, F1, bl, bh);
        w0 = x0; w1 = x1; x0 = nw0; x1 = nw1;
    }
    c.u = *(const uint4*)(Bo + n*16 + q*4); bf16x8 ao = c.h;
    OA = MF(ao, bb0, Z);
    OB = MF(ao, bb1, Z);
}

// ---------------------------------------------------------------------------
// Weight packing (pi layout): dword d of row n = (W[base+d][n], W[base+d+16][n])
// If lng != nullptr, the preceding LayerNorm's gamma is folded in.
// ---------------------------------------------------------------------------
__global__ __launch_bounds__(256) void pack_kernel(
    const float* __restrict__ Win, const float* __restrict__ Wh,
    const float* __restrict__ Wout, const float* __restrict__ lng,
    u32* __restrict__ dst, int din, int dout, int KP)
{
    int t = blockIdx.x * blockDim.x + threadIdx.x;
    int indw = 32*(KP/2);
    int tot = indw + 16384 + 256;
    if (t >= tot) return;
    float lo, hi;
    if (t < indw) {
        int nrow = t / (KP/2), rem = t % (KP/2);
        int T = rem >> 4, d = rem & 15;
        int klo = T*32 + d, khi = klo + 16;
        lo = (klo < din) ? Win[klo*32 + nrow] : 0.f;
        hi = (khi < din) ? Win[khi*32 + nrow] : 0.f;
    } else if (t < indw + 16384) {
        int u = t - indw; int l = u >> 9; int v = u & 511;
        int nrow = v >> 4; int d = v & 15;
        lo = Wh[l*1024 + d*32 + nrow];
        hi = Wh[l*1024 + (d+16)*32 + nrow];
        if (lng) { lo *= lng[l*32 + d]; hi *= lng[l*32 + d + 16]; }
    } else {
        int u = t - indw - 16384; int nrow = u >> 4; int d = u & 15;
        lo = (nrow < dout) ? Wout[d*dout + nrow] : 0.f;
        hi = (nrow < dout) ? Wout[(d+16)*dout + nrow] : 0.f;
        if (lng) { lo *= lng[1024 + d]; hi *= lng[1024 + d + 16]; }
    }
    dst[t] = pk2(lo, hi);
}

// ---------------------------------------------------------------------------
// Fold LN beta into the next matmul's bias.
// ---------------------------------------------------------------------------
__global__ __launch_bounds__(256) void fold_bias_kernel(
    const float* __restrict__ Wh,   const float* __restrict__ bh,
    const float* __restrict__ Wout, const float* __restrict__ bout,
    const float* __restrict__ lnb,  float* __restrict__ fb)
{
    int j = blockIdx.x * blockDim.x + threadIdx.x;
    if (j < 1024) {
        int l = j >> 5, jj = j & 31;
        float acc = bh[j];
        #pragma unroll
        for (int k = 0; k < 32; ++k)
            acc = fmaf(lnb[l*32 + k], Wh[l*1024 + k*32 + jj], acc);
        fb[j] = acc;
    } else if (j < 1024 + 16) {
        int jj = j - 1024;
        float acc = bout[jj];
        #pragma unroll
        for (int k = 0; k < 32; ++k)
            acc = fmaf(lnb[1024 + k], Wout[k*16 + jj], acc);
        fb[j] = acc;
    }
}

// ---------------------------------------------------------------------------
// Staging helpers (one element per lane; lanes q>=2 contribute zeros).
// ---------------------------------------------------------------------------
__device__ __forceinline__ bf16x8 stage_node(
    const float* __restrict__ nodes, float g, int e, int q)
{
    uint4 w; w.x = 0u; w.y = 0u; w.z = 0u; w.w = 0u;
    if (q == 0) {
        float2 v01 = *(const float2*)(nodes + (size_t)e*6);
        float2 v23 = *(const float2*)(nodes + (size_t)e*6 + 2);
        w.x = pk2(v01.x, 0.f); w.y = pk2(v01.y, 0.f);
        w.z = pk2(v23.x, 0.f); w.w = pk2(v23.y, 0.f);
    } else if (q == 1) {
        float2 v45 = *(const float2*)(nodes + (size_t)e*6 + 4);
        w.x = pk2(v45.x, 0.f); w.y = pk2(v45.y, 0.f);
        w.z = pk2(g, 0.f);
    }
    U4 c; c.u = w; return c.h;
}

__device__ __forceinline__ bf16x8 stage_edge(
    const float* __restrict__ nodes, const float* __restrict__ edges,
    const int* __restrict__ senders, const int* __restrict__ receivers,
    int e, int b, int q)
{
    uint4 w; w.x = 0u; w.y = 0u; w.z = 0u; w.w = 0u;
    if (q < 2) {
        int s = senders[e], r = receivers[e];
        const float* ps = nodes + ((size_t)b*NN + s)*6;
        const float* pr = nodes + ((size_t)b*NN + r)*6;
        float2 s01 = *(const float2*)ps; float s2v = ps[2];
        float2 r01 = *(const float2*)pr; float r2v = pr[2];
        float r0 = s01.x - r01.x, r1 = s01.y - r01.y, r2 = s2v - r2v;
        if (q == 0) {
            w.x = pk2(edges[e], 0.f); w.y = pk2(r0, 0.f);
            w.z = pk2(r1, 0.f);       w.w = pk2(r2, 0.f);
        } else {
            w.x = pk2(sqrtf(r0*r0 + r1*r1 + r2*r2), 0.f);
        }
    }
    U4 c; c.u = w; return c.h;
}

// ---------------------------------------------------------------------------
// Kernels. Block = 256 thr = 4 waves; each wave owns 32 elements
// (two groups of 16: A = e0..e0+15, B = e0+16..e0+31).
// ---------------------------------------------------------------------------
#define WAVE_SETUP \
    const int lane = threadIdx.x & 63; \
    const int wid  = threadIdx.x >> 6; \
    const int n = lane & 15, q = lane >> 4;

__global__ __launch_bounds__(256, 4) void encode_kernel(
    const float* __restrict__ nodes, const float* __restrict__ edges,
    const float* __restrict__ gvec,
    const int* __restrict__ senders, const int* __restrict__ receivers,
    const u32* __restrict__ Wne, const float* __restrict__ ne_bin,
    const float* __restrict__ ne_bh, const float* __restrict__ ne_bout,
    const u32* __restrict__ Wed, const float* __restrict__ ed_bin,
    const float* __restrict__ ed_bh, const float* __restrict__ ed_bout,
    float* __restrict__ ve, float* __restrict__ ee)
{
    WAVE_SETUP
    const bool edge_stage = blockIdx.x >= 512;
    const int lb = edge_stage ? (blockIdx.x - 512) : blockIdx.x;
    const int e0 = (lb*4 + wid) * 32;
    const int eA = e0 + n, eB = e0 + 16 + n;
    const int bA = eA >> 15, bB = eB >> 15;
    bf16x8 aA, aB;
    if (!edge_stage) {
        aA = stage_node(nodes, gvec[bA], eA, q);
        aB = stage_node(nodes, gvec[bB], eB, q);
    } else {
        aA = stage_edge(nodes, edges, senders, receivers, eA, bA, q);
        aB = stage_edge(nodes, edges, senders, receivers, eB, bB, q);
    }
    const u32*   Wp   = edge_stage ? Wed    : Wne;
    const float* pbin = edge_stage ? ed_bin : ne_bin;
    const float* pbh  = edge_stage ? ed_bh  : ne_bh;
    const float* pbo  = edge_stage ? ed_bout: ne_bout;
    float* dst        = edge_stage ? ee     : ve;
    f32x4 DA, DB;
    mlp_core2<1, false>(&aA, &aB, Wp, pbin, pbh, n, q, DA, DB);
    float4 bo = *(const float4*)(pbo + q*4);
    float4 st;
    st.x = fmaxf(DA[0] + bo.x, 0.f); st.y = fmaxf(DA[1] + bo.y, 0.f);
    st.z = fmaxf(DA[2] + bo.z, 0.f); st.w = fmaxf(DA[3] + bo.w, 0.f);
    *(float4*)(dst + (size_t)eA*16 + q*4) = st;
    st.x = fmaxf(DB[0] + bo.x, 0.f); st.y = fmaxf(DB[1] + bo.y, 0.f);
    st.z = fmaxf(DB[2] + bo.z, 0.f); st.w = fmaxf(DB[3] + bo.w, 0.f);
    *(float4*)(dst + (size_t)eB*16 + q*4) = st;
}

__global__ __launch_bounds__(256, 2) void edge_update_kernel(
    const float* __restrict__ gvec,
    const int* __restrict__ senders, const int* __restrict__ receivers,
    const float* __restrict__ ve, float* __restrict__ ee, float* __restrict__ agg,
    const u32* __restrict__ Wp, const float* __restrict__ bin,
    const float* __restrict__ fb)
{
    __shared__ __align__(16) float Xs[4*320];
    WAVE_SETUP
    float* X = Xs + wid*320;
    const int e0 = (blockIdx.x*4 + wid) * 32;
    const int eA = e0 + n, eB = e0 + 16 + n;
    const int bA = eA >> 15, bB = eB >> 15;
    const int sA = senders[eA], rA = receivers[eA];
    const int sB = senders[eB], rB = receivers[eB];
    float gA = gvec[bA], gB = gvec[bB];
    bf16x8 aA[2], aB[2];
    {
        float4 eev = *(const float4*)(ee + (size_t)eA*16 + q*4);
        float4 vsv = *(const float4*)(ve + ((size_t)bA*NN + sA)*16 + q*4);
        float4 vrv = *(const float4*)(ve + ((size_t)bA*NN + rA)*16 + q*4);
        U4 c;
        c.u.x = pk2(eev.x, vsv.x); c.u.y = pk2(eev.y, vsv.y);
        c.u.z = pk2(eev.z, vsv.z); c.u.w = pk2(eev.w, vsv.w);
        aA[0] = c.h;
        c.u.x = pk2(vrv.x, (q == 0) ? gA : 0.f);
        c.u.y = pk2(vrv.y, 0.f); c.u.z = pk2(vrv.z, 0.f); c.u.w = pk2(vrv.w, 0.f);
        aA[1] = c.h;
    }
    {
        float4 eev = *(const float4*)(ee + (size_t)eB*16 + q*4);
        float4 vsv = *(const float4*)(ve + ((size_t)bB*NN + sB)*16 + q*4);
        float4 vrv = *(const float4*)(ve + ((size_t)bB*NN + rB)*16 + q*4);
        U4 c;
        c.u.x = pk2(eev.x, vsv.x); c.u.y = pk2(eev.y, vsv.y);
        c.u.z = pk2(eev.z, vsv.z); c.u.w = pk2(eev.w, vsv.w);
        aB[0] = c.h;
        c.u.x = pk2(vrv.x, (q == 0) ? gB : 0.f);
        c.u.y = pk2(vrv.y, 0.f); c.u.z = pk2(vrv.z, 0.f); c.u.w = pk2(vrv.w, 0.f);
        aB[1] = c.h;
    }
    f32x4 DA, DB;
    mlp_core2<2, true>(aA, aB, Wp, bin, fb, n, q, DA, DB);
    float4 bo = *(const float4*)(fb + 1024 + q*4);
    float4 stA, stB;
    stA.x = fmaxf(DA[0] + bo.x, 0.f); stA.y = fmaxf(DA[1] + bo.y, 0.f);
    stA.z = fmaxf(DA[2] + bo.z, 0.f); stA.w = fmaxf(DA[3] + bo.w, 0.f);
    stB.x = fmaxf(DB[0] + bo.x, 0.f); stB.y = fmaxf(DB[1] + bo.y, 0.f);
    stB.z = fmaxf(DB[2] + bo.z, 0.f); stB.w = fmaxf(DB[3] + bo.w, 0.f);
    *(float4*)(ee + (size_t)eA*16 + q*4) = stA;
    *(float4*)(ee + (size_t)eB*16 + q*4) = stB;
    // Coalesced atomics: transpose each group once through wave-private LDS
    // so one atomic instruction hits 4 receiver lines (16 lanes share one).
    *(float4*)(X + n*20 + q*4) = stA;
    #pragma unroll
    for (int rr = 0; rr < 4; ++rr) {
        int em = e0 + q*4 + rr;
        float v = X[(q*4+rr)*20 + n];
        int rc = __shfl(rA, q*4 + rr);
        atomicAdd(agg + ((size_t)(em >> 15)*NN + rc)*16 + n, v);
    }
    *(float4*)(X + n*20 + q*4) = stB;
    #pragma unroll
    for (int rr = 0; rr < 4; ++rr) {
        int em = e0 + 16 + q*4 + rr;
        float v = X[(q*4+rr)*20 + n];
        int rc = __shfl(rB, q*4 + rr);
        atomicAdd(agg + ((size_t)(em >> 15)*NN + rc)*16 + n, v);
    }
}

__global__ __launch_bounds__(256, 2) void node_update_kernel(
    const float* __restrict__ gvec,
    const float* __restrict__ agg, float* __restrict__ ve,
    const u32* __restrict__ Wp, const float* __restrict__ bin,
    const float* __restrict__ fb)
{
    WAVE_SETUP
    const int e0 = (blockIdx.x*4 + wid) * 32;
    const int eA = e0 + n, eB = e0 + 16 + n;
    const int bA = eA >> 15, bB = eB >> 15;
    float gA = gvec[bA], gB = gvec[bB];
    bf16x8 aA[2], aB[2];
    {
        float4 agv = *(const float4*)(agg + (size_t)eA*16 + q*4);
        float4 vev = *(const float4*)(ve  + (size_t)eA*16 + q*4);
        U4 c;
        c.u.x = pk2(agv.x, vev.x); c.u.y = pk2(agv.y, vev.y);
        c.u.z = pk2(agv.z, vev.z); c.u.w = pk2(agv.w, vev.w);
        aA[0] = c.h;
        c.u.x = (q == 0) ? pk2(gA, 0.f) : 0u;
        c.u.y = 0u; c.u.z = 0u; c.u.w = 0u;
        aA[1] = c.h;
    }
    {
        float4 agv = *(const float4*)(agg + (size_t)eB*16 + q*4);
        float4 vev = *(const float4*)(ve  + (size_t)eB*16 + q*4);
        U4 c;
        c.u.x = pk2(agv.x, vev.x); c.u.y = pk2(agv.y, vev.y);
        c.u.z = pk2(agv.z, vev.z); c.u.w = pk2(agv.w, vev.w);
        aB[0] = c.h;
        c.u.x = (q == 0) ? pk2(gB, 0.f) : 0u;
        c.u.y = 0u; c.u.z = 0u; c.u.w = 0u;
        aB[1] = c.h;
    }
    f32x4 DA, DB;
    mlp_core2<2, true>(aA, aB, Wp, bin, fb, n, q, DA, DB);
    float4 bo = *(const float4*)(fb + 1024 + q*4);
    float4 st;
    st.x = fmaxf(DA[0] + bo.x, 0.f); st.y = fmaxf(DA[1] + bo.y, 0.f);
    st.z = fmaxf(DA[2] + bo.z, 0.f); st.w = fmaxf(DA[3] + bo.w, 0.f);
    *(float4*)(ve + (size_t)eA*16 + q*4) = st;
    st.x = fmaxf(DB[0] + bo.x, 0.f); st.y = fmaxf(DB[1] + bo.y, 0.f);
    st.z = fmaxf(DB[2] + bo.z, 0.f); st.w = fmaxf(DB[3] + bo.w, 0.f);
    *(float4*)(ve + (size_t)eB*16 + q*4) = st;
}

__global__ __launch_bounds__(256, 2) void decode_kernel(
    const float* __restrict__ ve,
    const u32* __restrict__ Wp, const float* __restrict__ bin,
    const float* __restrict__ bh, const float* __restrict__ bout,
    float* __restrict__ out)
{
    WAVE_SETUP
    const int e0 = (blockIdx.x*4 + wid) * 32;
    const int eA = e0 + n, eB = e0 + 16 + n;
    bf16x8 aA, aB;
    {
        float4 v = *(const float4*)(ve + (size_t)eA*16 + q*4);
        U4 c;
        c.u.x = pk2(v.x, 0.f); c.u.y = pk2(v.y, 0.f);
        c.u.z = pk2(v.z, 0.f); c.u.w = pk2(v.w, 0.f);
        aA = c.h;
    }
    {
        float4 v = *(const float4*)(ve + (size_t)eB*16 + q*4);
        U4 c;
        c.u.x = pk2(v.x, 0.f); c.u.y = pk2(v.y, 0.f);
        c.u.z = pk2(v.z, 0.f); c.u.w = pk2(v.w, 0.f);
        aB = c.h;
    }
    f32x4 DA, DB;
    mlp_core2<1, false>(&aA, &aB, Wp, bin, bh, n, q, DA, DB);
    if (q == 0) {
        out[(size_t)eA*3 + 0] = fmaxf(DA[0] + bout[0], 0.f);
        out[(size_t)eA*3 + 1] = fmaxf(DA[1] + bout[1], 0.f);
        out[(size_t)eA*3 + 2] = fmaxf(DA[2] + bout[2], 0.f);
        out[(size_t)eB*3 + 0] = fmaxf(DB[0] + bout[0], 0.f);
        out[(size_t)eB*3 + 1] = fmaxf(DB[1] + bout[1], 0.f);
        out[(size_t)eB*3 + 2] = fmaxf(DB[2] + bout[2], 0.f);
    }
}

// ---------------------------------------------------------------------------
// launch
// ---------------------------------------------------------------------------
extern "C" void kernel_launch(void* const* d_in, const int* in_sizes, int n_in,
                              void* d_out, int out_size, void* d_ws, size_t ws_size,
                              hipStream_t stream)
{
    const float* nodes     = (const float*)d_in[0];
    const float* edges     = (const float*)d_in[1];
    const float* gvec      = (const float*)d_in[2];
    const int*   senders   = (const int*)  d_in[3];
    const int*   receivers = (const int*)  d_in[4];

    const float* ne_Win  = (const float*)d_in[5];
    const float* ne_bin  = (const float*)d_in[6];
    const float* ne_Wh   = (const float*)d_in[7];
    const float* ne_bh   = (const float*)d_in[8];
    const float* ne_Wout = (const float*)d_in[9];
    const float* ne_bout = (const float*)d_in[10];

    const float* ed_Win  = (const float*)d_in[11];
    const float* ed_bin  = (const float*)d_in[12];
    const float* ed_Wh   = (const float*)d_in[13];
    const float* ed_bh   = (const float*)d_in[14];
    const float* ed_Wout = (const float*)d_in[15];
    const float* ed_bout = (const float*)d_in[16];

    const float* pe_Win  = (const float*)d_in[17];
    const float* pe_bin  = (const float*)d_in[18];
    const float* pe_Wh   = (const float*)d_in[19];
    const float* pe_bh   = (const float*)d_in[20];
    const float* pe_Wout = (const float*)d_in[21];
    const float* pe_bout = (const float*)d_in[22];
    const float* pe_lng  = (const float*)d_in[23];
    const float* pe_lnb  = (const float*)d_in[24];

    const float* pv_Win  = (const float*)d_in[25];
    const float* pv_bin  = (const float*)d_in[26];
    const float* pv_Wh   = (const float*)d_in[27];
    const float* pv_bh   = (const float*)d_in[28];
    const float* pv_Wout = (const float*)d_in[29];
    const float* pv_bout = (const float*)d_in[30];
    const float* pv_lng  = (const float*)d_in[31];
    const float* pv_lnb  = (const float*)d_in[32];

    const float* de_Win  = (const float*)d_in[33];
    const float* de_bin  = (const float*)d_in[34];
    const float* de_Wh   = (const float*)d_in[35];
    const float* de_bh   = (const float*)d_in[36];
    const float* de_Wout = (const float*)d_in[37];
    const float* de_bout = (const float*)d_in[38];

    // workspace: ve | ee | agg (4 MB each) | packed bf16 weights | folded biases
    float* ve  = (float*)d_ws;
    float* ee  = ve + (size_t)1048576;
    float* agg = ee + (size_t)1048576;
    u32* Wne = (u32*)(agg + (size_t)1048576);
    u32* Wed = Wne + 17152;
    u32* Wpe = Wed + 17152;
    u32* Wpv = Wpe + 17664;
    u32* Wde = Wpv + 17664;
    float* Fpe = (float*)(Wde + 17152);
    float* Fpv = Fpe + 1040;

    const dim3 blk(256);

    pack_kernel<<<70, blk, 0, stream>>>(ne_Win, ne_Wh, ne_Wout, nullptr, Wne,  7, 16, 32);
    pack_kernel<<<70, blk, 0, stream>>>(ed_Win, ed_Wh, ed_Wout, nullptr, Wed,  5, 16, 32);
    pack_kernel<<<70, blk, 0, stream>>>(pe_Win, pe_Wh, pe_Wout, pe_lng,  Wpe, 49, 16, 64);
    pack_kernel<<<70, blk, 0, stream>>>(pv_Win, pv_Wh, pv_Wout, pv_lng,  Wpv, 33, 16, 64);
    pack_kernel<<<70, blk, 0, stream>>>(de_Win, de_Wh, de_Wout, nullptr, Wde, 16,  3, 32);
    fold_bias_kernel<<<5, blk, 0, stream>>>(pe_Wh, pe_bh, pe_Wout, pe_bout, pe_lnb, Fpe);
    fold_bias_kernel<<<5, blk, 0, stream>>>(pv_Wh, pv_bh, pv_Wout, pv_bout, pv_lnb, Fpv);

    encode_kernel<<<1024, blk, 0, stream>>>(nodes, edges, gvec, senders, receivers,
        Wne, ne_bin, ne_bh, ne_bout,
        Wed, ed_bin, ed_bh, ed_bout, ve, ee);

    for (int step = 0; step < 2; ++step) {
        hipMemsetAsync(agg, 0, (size_t)BB * NN * 16 * sizeof(float), stream);
        edge_update_kernel<<<512, blk, 0, stream>>>(gvec, senders, receivers,
            ve, ee, agg, Wpe, pe_bin, Fpe);
        node_update_kernel<<<512, blk, 0, stream>>>(gvec, agg, ve,
            Wpv, pv_bin, Fpv);
    }

    decode_kernel<<<512, blk, 0, stream>>>(ve,
        Wde, de_bin, de_bh, de_bout, (float*)d_out);
}

// Round 9
// 321.585 us; speedup vs baseline: 1.2717x; 1.0129x over previous
//
#include <hip/hip_runtime.h>

#define BB 2
#define NN 32768
#define EN 32768

typedef unsigned int u32;
typedef __attribute__((ext_vector_type(8))) short bf16x8;
typedef __attribute__((ext_vector_type(4))) float f32x4;

union U4 { uint4 u; bf16x8 h; };

// ---------------------------------------------------------------------------
// f32 pair -> packed bf16 dword (RNE). HW instr on gfx950 when available.
// ---------------------------------------------------------------------------
#if defined(__has_builtin)
#if __has_builtin(__builtin_amdgcn_cvt_pk_bf16_f32)
#define HAVE_CVT_PK 1
#endif
#endif

#ifdef HAVE_CVT_PK
typedef __attribute__((ext_vector_type(2))) __bf16 bfv2;
__device__ __forceinline__ u32 pk2(float lo, float hi) {
    bfv2 v = __builtin_amdgcn_cvt_pk_bf16_f32(lo, hi);
    return __builtin_bit_cast(u32, v);
}
#else
__device__ __forceinline__ u32 pk2(float lo, float hi) {
    u32 a = __builtin_bit_cast(u32, lo);
    u32 b = __builtin_bit_cast(u32, hi);
    a += 0x7FFFu + ((a >> 16) & 1u);
    b += 0x7FFFu + ((b >> 16) & 1u);
    return (a >> 16) | (b & 0xFFFF0000u);
}
#endif

__device__ __forceinline__ f32x4 MF(bf16x8 a, bf16x8 b, f32x4 c) {
    return __builtin_amdgcn_mfma_f32_16x16x32_bf16(a, b, c, 0, 0, 0);
}

// ---------------------------------------------------------------------------
// Layer epilogue (register-resident; LN affine pre-folded into weights).
// Weights = A-operand (m = out-feature), activations = B-operand (n = elem).
// Lane (n,q): out-feats q*4+r (D0) / 16+q*4+r (D1) of element n. Under the
// pi k-permutation pk2(y_lo[i], y_hi[i]) IS the next layer's B-frag dword i.
// ---------------------------------------------------------------------------
template<bool LN>
__device__ __forceinline__ bf16x8 transform(f32x4 D0, f32x4 D1,
                                            float4 bl, float4 bh)
{
    float y0 = fmaxf(D0[0] + bl.x, 0.f), y1 = fmaxf(D0[1] + bl.y, 0.f);
    float y2 = fmaxf(D0[2] + bl.z, 0.f), y3 = fmaxf(D0[3] + bl.w, 0.f);
    float z0 = fmaxf(D1[0] + bh.x, 0.f), z1 = fmaxf(D1[1] + bh.y, 0.f);
    float z2 = fmaxf(D1[2] + bh.z, 0.f), z3 = fmaxf(D1[3] + bh.w, 0.f);
    if (LN) {
        float s = ((y0+y1)+(y2+y3)) + ((z0+z1)+(z2+z3));
        float s2 = 0.f;
        s2 = fmaf(y0,y0,s2); s2 = fmaf(y1,y1,s2); s2 = fmaf(y2,y2,s2); s2 = fmaf(y3,y3,s2);
        s2 = fmaf(z0,z0,s2); s2 = fmaf(z1,z1,s2); s2 = fmaf(z2,z2,s2); s2 = fmaf(z3,z3,s2);
        s  += __shfl_xor(s, 16);  s  += __shfl_xor(s, 32);
        s2 += __shfl_xor(s2, 16); s2 += __shfl_xor(s2, 32);
        float mu  = s * (1.f/32.f);
        float var = fmaf(-mu, mu, s2 * (1.f/32.f));
        float rs  = rsqrtf(var + 1e-5f);
        float nt  = -mu * rs;
        y0 = fmaf(y0, rs, nt); y1 = fmaf(y1, rs, nt);
        y2 = fmaf(y2, rs, nt); y3 = fmaf(y3, rs, nt);
        z0 = fmaf(z0, rs, nt); z1 = fmaf(z1, rs, nt);
        z2 = fmaf(z2, rs, nt); z3 = fmaf(z3, rs, nt);
    }
    U4 c;
    c.u.x = pk2(y0, z0); c.u.y = pk2(y1, z1);
    c.u.z = pk2(y2, z2); c.u.w = pk2(y3, z3);
    return c.h;
}

// ---------------------------------------------------------------------------
// Block-level staging of packed weights + biases into LDS.
// Round 8 showed ~170cyc/layer recurring stall: 70KB weight set > 32KB L1,
// every layer's A-frag loads thrash L1 -> L2 latency. One bulk copy here,
// then per-layer ds_read (stable ~120cyc, covered by depth-2 reg prefetch).
// WB layout (floats): [0..32) bin | [32..1056) hidden biases | [1056..1072) out
// ---------------------------------------------------------------------------
__device__ __forceinline__ void stage_weights(
    u32* WL, float* WB, const u32* __restrict__ Wp,
    const float* __restrict__ bin, const float* __restrict__ bhid,
    const float* __restrict__ bo, int wtot, int nbo, int tid)
{
    for (int i = tid*4; i < wtot; i += 1024)
        *(uint4*)(WL + i) = *(const uint4*)(Wp + i);
    for (int i = tid; i < 1072; i += 256) {
        float v;
        if (i < 32)         v = bin[i];
        else if (i < 1056)  v = bhid[i-32];
        else                v = (i-1056 < nbo) ? bo[i-1056] : 0.f;
        WB[i] = v;
    }
    __syncthreads();
}

// ---------------------------------------------------------------------------
// Wave-level deep MLP over TWO independent 16-element groups, weights/biases
// from LDS. WL (pi layout): [Bin 32 x KT*16 dw][Bh 32 x 512 dw][Bo 256 dw]
// ---------------------------------------------------------------------------
template<int KT, bool LN>
__device__ __forceinline__ void mlp_core2(
    const bf16x8* bA, const bf16x8* bB,
    const u32* WL, const float* WB,
    int n, int q, f32x4& OA, f32x4& OB)
{
    const u32* Bh = WL + 32*KT*16;
    const u32* Bo = Bh + 16384;
    U4 c;
    const f32x4 Z = {0.f,0.f,0.f,0.f};
    f32x4 A0 = Z, A1 = Z, B0 = Z, B1 = Z;
    #pragma unroll
    for (int T = 0; T < KT; ++T) {
        c.u = *(const uint4*)(WL + n*(KT*16) + T*16 + q*4);      bf16x8 a0 = c.h;
        c.u = *(const uint4*)(WL + (n+16)*(KT*16) + T*16 + q*4); bf16x8 a1 = c.h;
        A0 = MF(a0, bA[T], A0); A1 = MF(a1, bA[T], A1);
        B0 = MF(a0, bB[T], B0); B1 = MF(a1, bB[T], B1);
    }
    // prefetch layer 0 and layer 1 weights (depth-2 register rotation)
    c.u = *(const uint4*)(Bh + n*16 + q*4);            bf16x8 w0 = c.h;
    c.u = *(const uint4*)(Bh + (n+16)*16 + q*4);       bf16x8 w1 = c.h;
    c.u = *(const uint4*)(Bh + 512 + n*16 + q*4);      bf16x8 x0 = c.h;
    c.u = *(const uint4*)(Bh + 512 + (n+16)*16 + q*4); bf16x8 x1 = c.h;
    float4 bl = *(const float4*)(WB + q*4);
    float4 bh = *(const float4*)(WB + q*4 + 16);
    bf16x8 bb0 = transform<LN>(A0, A1, bl, bh);
    bf16x8 bb1 = transform<LN>(B0, B1, bl, bh);
    #pragma unroll 1
    for (int l = 0; l < 32; ++l) {
        const int lp = (l+2 < 32) ? l+2 : 31;
        const u32* Bn = Bh + lp*512;
        c.u = *(const uint4*)(Bn + n*16 + q*4);       bf16x8 nw0 = c.h;
        c.u = *(const uint4*)(Bn + (n+16)*16 + q*4);  bf16x8 nw1 = c.h;
        bl = *(const float4*)(WB + 32 + l*32 + q*4);
        bh = *(const float4*)(WB + 32 + l*32 + q*4 + 16);
        f32x4 E0 = MF(w0, bb0, Z);
        f32x4 E1 = MF(w1, bb0, Z);
        f32x4 F0 = MF(w0, bb1, Z);
        f32x4 F1 = MF(w1, bb1, Z);
        bb0 = transform<LN>(E0, E1, bl, bh);
        bb1 = transform<LN>(F0, F1, bl, bh);
        w0 = x0; w1 = x1; x0 = nw0; x1 = nw1;
    }
    c.u = *(const uint4*)(Bo + n*16 + q*4); bf16x8 ao = c.h;
    OA = MF(ao, bb0, Z);
    OB = MF(ao, bb1, Z);
}

// ---------------------------------------------------------------------------
// Weight packing (pi layout) + LN-beta bias folding, merged into ONE kernel.
// blocks [0,70): ne  [70,140): ed  [140,210): pe  [210,280): pv  [280,350): de
// blocks [350,355): fold pe   [355,360): fold pv
// ---------------------------------------------------------------------------
__device__ __forceinline__ void pack_body(
    const float* __restrict__ Win, const float* __restrict__ Wh,
    const float* __restrict__ Wout, const float* __restrict__ lng,
    u32* __restrict__ dst, int din, int dout, int KP, int lb, int tid)
{
    int t = lb * 256 + tid;
    int indw = 32*(KP/2);
    int tot = indw + 16384 + 256;
    if (t >= tot) return;
    float lo, hi;
    if (t < indw) {
        int nrow = t / (KP/2), rem = t % (KP/2);
        int T = rem >> 4, d = rem & 15;
        int klo = T*32 + d, khi = klo + 16;
        lo = (klo < din) ? Win[klo*32 + nrow] : 0.f;
        hi = (khi < din) ? Win[khi*32 + nrow] : 0.f;
    } else if (t < indw + 16384) {
        int u = t - indw; int l = u >> 9; int v = u & 511;
        int nrow = v >> 4; int d = v & 15;
        lo = Wh[l*1024 + d*32 + nrow];
        hi = Wh[l*1024 + (d+16)*32 + nrow];
        if (lng) { lo *= lng[l*32 + d]; hi *= lng[l*32 + d + 16]; }
    } else {
        int u = t - indw - 16384; int nrow = u >> 4; int d = u & 15;
        lo = (nrow < dout) ? Wout[d*dout + nrow] : 0.f;
        hi = (nrow < dout) ? Wout[(d+16)*dout + nrow] : 0.f;
        if (lng) { lo *= lng[1024 + d]; hi *= lng[1024 + d + 16]; }
    }
    dst[t] = pk2(lo, hi);
}

__device__ __forceinline__ void fold_body(
    const float* __restrict__ Wh,   const float* __restrict__ bh,
    const float* __restrict__ Wout, const float* __restrict__ bout,
    const float* __restrict__ lnb,  float* __restrict__ fb, int lb, int tid)
{
    int j = lb * 256 + tid;
    if (j < 1024) {
        int l = j >> 5, jj = j & 31;
        float acc = bh[j];
        #pragma unroll
        for (int k = 0; k < 32; ++k)
            acc = fmaf(lnb[l*32 + k], Wh[l*1024 + k*32 + jj], acc);
        fb[j] = acc;
    } else if (j < 1024 + 16) {
        int jj = j - 1024;
        float acc = bout[jj];
        #pragma unroll
        for (int k = 0; k < 32; ++k)
            acc = fmaf(lnb[1024 + k], Wout[k*16 + jj], acc);
        fb[j] = acc;
    }
}

__global__ __launch_bounds__(256) void prep_kernel(
    const float* ne_Win, const float* ne_Wh, const float* ne_Wout,
    const float* ed_Win, const float* ed_Wh, const float* ed_Wout,
    const float* pe_Win, const float* pe_Wh, const float* pe_Wout,
    const float* pe_lng, const float* pe_lnb, const float* pe_bh, const float* pe_bout,
    const float* pv_Win, const float* pv_Wh, const float* pv_Wout,
    const float* pv_lng, const float* pv_lnb, const float* pv_bh, const float* pv_bout,
    const float* de_Win, const float* de_Wh, const float* de_Wout,
    u32* Wne, u32* Wed, u32* Wpe, u32* Wpv, u32* Wde,
    float* Fpe, float* Fpv)
{
    int bx = blockIdx.x, tid = threadIdx.x;
    if      (bx < 70)  pack_body(ne_Win, ne_Wh, ne_Wout, nullptr, Wne,  7, 16, 32, bx,       tid);
    else if (bx < 140) pack_body(ed_Win, ed_Wh, ed_Wout, nullptr, Wed,  5, 16, 32, bx - 70,  tid);
    else if (bx < 210) pack_body(pe_Win, pe_Wh, pe_Wout, pe_lng,  Wpe, 49, 16, 64, bx - 140, tid);
    else if (bx < 280) pack_body(pv_Win, pv_Wh, pv_Wout, pv_lng,  Wpv, 33, 16, 64, bx - 210, tid);
    else if (bx < 350) pack_body(de_Win, de_Wh, de_Wout, nullptr, Wde, 16,  3, 32, bx - 280, tid);
    else if (bx < 355) fold_body(pe_Wh, pe_bh, pe_Wout, pe_bout, pe_lnb, Fpe, bx - 350, tid);
    else               fold_body(pv_Wh, pv_bh, pv_Wout, pv_bout, pv_lnb, Fpv, bx - 355, tid);
}

// ---------------------------------------------------------------------------
// Staging helpers (one element per lane; lanes q>=2 contribute zeros).
// ---------------------------------------------------------------------------
__device__ __forceinline__ bf16x8 stage_node(
    const float* __restrict__ nodes, float g, int e, int q)
{
    uint4 w; w.x = 0u; w.y = 0u; w.z = 0u; w.w = 0u;
    if (q == 0) {
        float2 v01 = *(const float2*)(nodes + (size_t)e*6);
        float2 v23 = *(const float2*)(nodes + (size_t)e*6 + 2);
        w.x = pk2(v01.x, 0.f); w.y = pk2(v01.y, 0.f);
        w.z = pk2(v23.x, 0.f); w.w = pk2(v23.y, 0.f);
    } else if (q == 1) {
        float2 v45 = *(const float2*)(nodes + (size_t)e*6 + 4);
        w.x = pk2(v45.x, 0.f); w.y = pk2(v45.y, 0.f);
        w.z = pk2(g, 0.f);
    }
    U4 c; c.u = w; return c.h;
}

__device__ __forceinline__ bf16x8 stage_edge(
    const float* __restrict__ nodes, const float* __restrict__ edges,
    const int* __restrict__ senders, const int* __restrict__ receivers,
    int e, int b, int q)
{
    uint4 w; w.x = 0u; w.y = 0u; w.z = 0u; w.w = 0u;
    if (q < 2) {
        int s = senders[e], r = receivers[e];
        const float* ps = nodes + ((size_t)b*NN + s)*6;
        const float* pr = nodes + ((size_t)b*NN + r)*6;
        float2 s01 = *(const float2*)ps; float s2v = ps[2];
        float2 r01 = *(const float2*)pr; float r2v = pr[2];
        float r0 = s01.x - r01.x, r1 = s01.y - r01.y, r2 = s2v - r2v;
        if (q == 0) {
            w.x = pk2(edges[e], 0.f); w.y = pk2(r0, 0.f);
            w.z = pk2(r1, 0.f);       w.w = pk2(r2, 0.f);
        } else {
            w.x = pk2(sqrtf(r0*r0 + r1*r1 + r2*r2), 0.f);
        }
    }
    U4 c; c.u = w; return c.h;
}

// ---------------------------------------------------------------------------
// Kernels. Block = 256 thr = 4 waves; each wave owns 32 elements
// (two groups of 16). LDS: weights+biases (~73-80KB) -> 2 blocks/CU.
// ---------------------------------------------------------------------------
#define WAVE_SETUP \
    const int lane = threadIdx.x & 63; \
    const int wid  = threadIdx.x >> 6; \
    const int n = lane & 15, q = lane >> 4;

__global__ __launch_bounds__(256, 2) void encode_kernel(
    const float* __restrict__ nodes, const float* __restrict__ edges,
    const float* __restrict__ gvec,
    const int* __restrict__ senders, const int* __restrict__ receivers,
    const u32* __restrict__ Wne, const float* __restrict__ ne_bin,
    const float* __restrict__ ne_bh, const float* __restrict__ ne_bout,
    const u32* __restrict__ Wed, const float* __restrict__ ed_bin,
    const float* __restrict__ ed_bh, const float* __restrict__ ed_bout,
    float* __restrict__ ve, float* __restrict__ ee)
{
    __shared__ __align__(16) u32 SL[17152 + 1072];
    u32* WL = SL;
    float* WB = (float*)(SL + 17152);
    WAVE_SETUP
    const bool edge_stage = blockIdx.x >= 512;
    stage_weights(WL, WB,
                  edge_stage ? Wed : Wne,
                  edge_stage ? ed_bin : ne_bin,
                  edge_stage ? ed_bh : ne_bh,
                  edge_stage ? ed_bout : ne_bout,
                  17152, 16, threadIdx.x);
    const int lb = edge_stage ? (blockIdx.x - 512) : blockIdx.x;
    const int e0 = (lb*4 + wid) * 32;
    const int eA = e0 + n, eB = e0 + 16 + n;
    const int bA = eA >> 15, bB = eB >> 15;
    bf16x8 aA, aB;
    if (!edge_stage) {
        aA = stage_node(nodes, gvec[bA], eA, q);
        aB = stage_node(nodes, gvec[bB], eB, q);
    } else {
        aA = stage_edge(nodes, edges, senders, receivers, eA, bA, q);
        aB = stage_edge(nodes, edges, senders, receivers, eB, bB, q);
    }
    float* dst = edge_stage ? ee : ve;
    f32x4 DA, DB;
    mlp_core2<1, false>(&aA, &aB, WL, WB, n, q, DA, DB);
    float4 bo = *(const float4*)(WB + 1056 + q*4);
    float4 st;
    st.x = fmaxf(DA[0] + bo.x, 0.f); st.y = fmaxf(DA[1] + bo.y, 0.f);
    st.z = fmaxf(DA[2] + bo.z, 0.f); st.w = fmaxf(DA[3] + bo.w, 0.f);
    *(float4*)(dst + (size_t)eA*16 + q*4) = st;
    st.x = fmaxf(DB[0] + bo.x, 0.f); st.y = fmaxf(DB[1] + bo.y, 0.f);
    st.z = fmaxf(DB[2] + bo.z, 0.f); st.w = fmaxf(DB[3] + bo.w, 0.f);
    *(float4*)(dst + (size_t)eB*16 + q*4) = st;
}

__global__ __launch_bounds__(256, 2) void edge_update_kernel(
    const float* __restrict__ gvec,
    const int* __restrict__ senders, const int* __restrict__ receivers,
    const float* __restrict__ ve, float* __restrict__ ee, float* __restrict__ agg,
    const u32* __restrict__ Wp, const float* __restrict__ bin,
    const float* __restrict__ fb)
{
    __shared__ __align__(16) u32 SL[17664 + 1072 + 1280];
    u32* WL = SL;
    float* WB = (float*)(SL + 17664);
    WAVE_SETUP
    float* X = (float*)(SL + 18736) + wid*320;
    stage_weights(WL, WB, Wp, bin, fb, fb + 1024, 17664, 16, threadIdx.x);
    const int e0 = (blockIdx.x*4 + wid) * 32;
    const int eA = e0 + n, eB = e0 + 16 + n;
    const int bA = eA >> 15, bB = eB >> 15;
    const int sA = senders[eA], rA = receivers[eA];
    const int sB = senders[eB], rB = receivers[eB];
    float gA = gvec[bA], gB = gvec[bB];
    bf16x8 aA[2], aB[2];
    {
        float4 eev = *(const float4*)(ee + (size_t)eA*16 + q*4);
        float4 vsv = *(const float4*)(ve + ((size_t)bA*NN + sA)*16 + q*4);
        float4 vrv = *(const float4*)(ve + ((size_t)bA*NN + rA)*16 + q*4);
        U4 c;
        c.u.x = pk2(eev.x, vsv.x); c.u.y = pk2(eev.y, vsv.y);
        c.u.z = pk2(eev.z, vsv.z); c.u.w = pk2(eev.w, vsv.w);
        aA[0] = c.h;
        c.u.x = pk2(vrv.x, (q == 0) ? gA : 0.f);
        c.u.y = pk2(vrv.y, 0.f); c.u.z = pk2(vrv.z, 0.f); c.u.w = pk2(vrv.w, 0.f);
        aA[1] = c.h;
    }
    {
        float4 eev = *(const float4*)(ee + (size_t)eB*16 + q*4);
        float4 vsv = *(const float4*)(ve + ((size_t)bB*NN + sB)*16 + q*4);
        float4 vrv = *(const float4*)(ve + ((size_t)bB*NN + rB)*16 + q*4);
        U4 c;
        c.u.x = pk2(eev.x, vsv.x); c.u.y = pk2(eev.y, vsv.y);
        c.u.z = pk2(eev.z, vsv.z); c.u.w = pk2(eev.w, vsv.w);
        aB[0] = c.h;
        c.u.x = pk2(vrv.x, (q == 0) ? gB : 0.f);
        c.u.y = pk2(vrv.y, 0.f); c.u.z = pk2(vrv.z, 0.f); c.u.w = pk2(vrv.w, 0.f);
        aB[1] = c.h;
    }
    f32x4 DA, DB;
    mlp_core2<2, true>(aA, aB, WL, WB, n, q, DA, DB);
    float4 bo = *(const float4*)(WB + 1056 + q*4);
    float4 stA, stB;
    stA.x = fmaxf(DA[0] + bo.x, 0.f); stA.y = fmaxf(DA[1] + bo.y, 0.f);
    stA.z = fmaxf(DA[2] + bo.z, 0.f); stA.w = fmaxf(DA[3] + bo.w, 0.f);
    stB.x = fmaxf(DB[0] + bo.x, 0.f); stB.y = fmaxf(DB[1] + bo.y, 0.f);
    stB.z = fmaxf(DB[2] + bo.z, 0.f); stB.w = fmaxf(DB[3] + bo.w, 0.f);
    *(float4*)(ee + (size_t)eA*16 + q*4) = stA;
    *(float4*)(ee + (size_t)eB*16 + q*4) = stB;
    // Coalesced atomics: transpose each group through wave-private LDS so one
    // atomic instruction hits 4 receiver lines (16 lanes share a receiver).
    *(float4*)(X + n*20 + q*4) = stA;
    #pragma unroll
    for (int rr = 0; rr < 4; ++rr) {
        int em = e0 + q*4 + rr;
        float v = X[(q*4+rr)*20 + n];
        int rc = __shfl(rA, q*4 + rr);
        atomicAdd(agg + ((size_t)(em >> 15)*NN + rc)*16 + n, v);
    }
    *(float4*)(X + n*20 + q*4) = stB;
    #pragma unroll
    for (int rr = 0; rr < 4; ++rr) {
        int em = e0 + 16 + q*4 + rr;
        float v = X[(q*4+rr)*20 + n];
        int rc = __shfl(rB, q*4 + rr);
        atomicAdd(agg + ((size_t)(em >> 15)*NN + rc)*16 + n, v);
    }
}

__global__ __launch_bounds__(256, 2) void node_update_kernel(
    const float* __restrict__ gvec,
    const float* __restrict__ agg, float* __restrict__ ve,
    const u32* __restrict__ Wp, const float* __restrict__ bin,
    const float* __restrict__ fb)
{
    __shared__ __align__(16) u32 SL[17664 + 1072];
    u32* WL = SL;
    float* WB = (float*)(SL + 17664);
    WAVE_SETUP
    stage_weights(WL, WB, Wp, bin, fb, fb + 1024, 17664, 16, threadIdx.x);
    const int e0 = (blockIdx.x*4 + wid) * 32;
    const int eA = e0 + n, eB = e0 + 16 + n;
    const int bA = eA >> 15, bB = eB >> 15;
    float gA = gvec[bA], gB = gvec[bB];
    bf16x8 aA[2], aB[2];
    {
        float4 agv = *(const float4*)(agg + (size_t)eA*16 + q*4);
        float4 vev = *(const float4*)(ve  + (size_t)eA*16 + q*4);
        U4 c;
        c.u.x = pk2(agv.x, vev.x); c.u.y = pk2(agv.y, vev.y);
        c.u.z = pk2(agv.z, vev.z); c.u.w = pk2(agv.w, vev.w);
        aA[0] = c.h;
        c.u.x = (q == 0) ? pk2(gA, 0.f) : 0u;
        c.u.y = 0u; c.u.z = 0u; c.u.w = 0u;
        aA[1] = c.h;
    }
    {
        float4 agv = *(const float4*)(agg + (size_t)eB*16 + q*4);
        float4 vev = *(const float4*)(ve  + (size_t)eB*16 + q*4);
        U4 c;
        c.u.x = pk2(agv.x, vev.x); c.u.y = pk2(agv.y, vev.y);
        c.u.z = pk2(agv.z, vev.z); c.u.w = pk2(agv.w, vev.w);
        aB[0] = c.h;
        c.u.x = (q == 0) ? pk2(gB, 0.f) : 0u;
        c.u.y = 0u; c.u.z = 0u; c.u.w = 0u;
        aB[1] = c.h;
    }
    f32x4 DA, DB;
    mlp_core2<2, true>(aA, aB, WL, WB, n, q, DA, DB);
    float4 bo = *(const float4*)(WB + 1056 + q*4);
    float4 st;
    st.x = fmaxf(DA[0] + bo.x, 0.f); st.y = fmaxf(DA[1] + bo.y, 0.f);
    st.z = fmaxf(DA[2] + bo.z, 0.f); st.w = fmaxf(DA[3] + bo.w, 0.f);
    *(float4*)(ve + (size_t)eA*16 + q*4) = st;
    st.x = fmaxf(DB[0] + bo.x, 0.f); st.y = fmaxf(DB[1] + bo.y, 0.f);
    st.z = fmaxf(DB[2] + bo.z, 0.f); st.w = fmaxf(DB[3] + bo.w, 0.f);
    *(float4*)(ve + (size_t)eB*16 + q*4) = st;
}

__global__ __launch_bounds__(256, 2) void decode_kernel(
    const float* __restrict__ ve,
    const u32* __restrict__ Wp, const float* __restrict__ bin,
    const float* __restrict__ bh, const float* __restrict__ bout,
    float* __restrict__ out)
{
    __shared__ __align__(16) u32 SL[17152 + 1072];
    u32* WL = SL;
    float* WB = (float*)(SL + 17152);
    WAVE_SETUP
    stage_weights(WL, WB, Wp, bin, bh, bout, 17152, 3, threadIdx.x);
    const int e0 = (blockIdx.x*4 + wid) * 32;
    const int eA = e0 + n, eB = e0 + 16 + n;
    bf16x8 aA, aB;
    {
        float4 v = *(const float4*)(ve + (size_t)eA*16 + q*4);
        U4 c;
        c.u.x = pk2(v.x, 0.f); c.u.y = pk2(v.y, 0.f);
        c.u.z = pk2(v.z, 0.f); c.u.w = pk2(v.w, 0.f);
        aA = c.h;
    }
    {
        float4 v = *(const float4*)(ve + (size_t)eB*16 + q*4);
        U4 c;
        c.u.x = pk2(v.x, 0.f); c.u.y = pk2(v.y, 0.f);
        c.u.z = pk2(v.z, 0.f); c.u.w = pk2(v.w, 0.f);
        aB = c.h;
    }
    f32x4 DA, DB;
    mlp_core2<1, false>(&aA, &aB, WL, WB, n, q, DA, DB);
    if (q == 0) {
        float b0 = WB[1056], b1 = WB[1057], b2 = WB[1058];
        out[(size_t)eA*3 + 0] = fmaxf(DA[0] + b0, 0.f);
        out[(size_t)eA*3 + 1] = fmaxf(DA[1] + b1, 0.f);
        out[(size_t)eA*3 + 2] = fmaxf(DA[2] + b2, 0.f);
        out[(size_t)eB*3 + 0] = fmaxf(DB[0] + b0, 0.f);
        out[(size_t)eB*3 + 1] = fmaxf(DB[1] + b1, 0.f);
        out[(size_t)eB*3 + 2] = fmaxf(DB[2] + b2, 0.f);
    }
}

// ---------------------------------------------------------------------------
// launch
// ---------------------------------------------------------------------------
extern "C" void kernel_launch(void* const* d_in, const int* in_sizes, int n_in,
                              void* d_out, int out_size, void* d_ws, size_t ws_size,
                              hipStream_t stream)
{
    const float* nodes     = (const float*)d_in[0];
    const float* edges     = (const float*)d_in[1];
    const float* gvec      = (const float*)d_in[2];
    const int*   senders   = (const int*)  d_in[3];
    const int*   receivers = (const int*)  d_in[4];

    const float* ne_Win  = (const float*)d_in[5];
    const float* ne_bin  = (const float*)d_in[6];
    const float* ne_Wh   = (const float*)d_in[7];
    const float* ne_bh   = (const float*)d_in[8];
    const float* ne_Wout = (const float*)d_in[9];
    const float* ne_bout = (const float*)d_in[10];

    const float* ed_Win  = (const float*)d_in[11];
    const float* ed_bin  = (const float*)d_in[12];
    const float* ed_Wh   = (const float*)d_in[13];
    const float* ed_bh   = (const float*)d_in[14];
    const float* ed_Wout = (const float*)d_in[15];
    const float* ed_bout = (const float*)d_in[16];

    const float* pe_Win  = (const float*)d_in[17];
    const float* pe_bin  = (const float*)d_in[18];
    const float* pe_Wh   = (const float*)d_in[19];
    const float* pe_bh   = (const float*)d_in[20];
    const float* pe_Wout = (const float*)d_in[21];
    const float* pe_bout = (const float*)d_in[22];
    const float* pe_lng  = (const float*)d_in[23];
    const float* pe_lnb  = (const float*)d_in[24];

    const float* pv_Win  = (const float*)d_in[25];
    const float* pv_bin  = (const float*)d_in[26];
    const float* pv_Wh   = (const float*)d_in[27];
    const float* pv_bh   = (const float*)d_in[28];
    const float* pv_Wout = (const float*)d_in[29];
    const float* pv_bout = (const float*)d_in[30];
    const float* pv_lng  = (const float*)d_in[31];
    const float* pv_lnb  = (const float*)d_in[32];

    const float* de_Win  = (const float*)d_in[33];
    const float* de_bin  = (const float*)d_in[34];
    const float* de_Wh   = (const float*)d_in[35];
    const float* de_bh   = (const float*)d_in[36];
    const float* de_Wout = (const float*)d_in[37];
    const float* de_bout = (const float*)d_in[38];

    // workspace: ve | ee | agg (4 MB each) | packed bf16 weights | folded biases
    float* ve  = (float*)d_ws;
    float* ee  = ve + (size_t)1048576;
    float* agg = ee + (size_t)1048576;
    u32* Wne = (u32*)(agg + (size_t)1048576);
    u32* Wed = Wne + 17152;
    u32* Wpe = Wed + 17152;
    u32* Wpv = Wpe + 17664;
    u32* Wde = Wpv + 17664;
    float* Fpe = (float*)(Wde + 17152);
    float* Fpv = Fpe + 1040;

    const dim3 blk(256);

    prep_kernel<<<360, blk, 0, stream>>>(
        ne_Win, ne_Wh, ne_Wout,
        ed_Win, ed_Wh, ed_Wout,
        pe_Win, pe_Wh, pe_Wout, pe_lng, pe_lnb, pe_bh, pe_bout,
        pv_Win, pv_Wh, pv_Wout, pv_lng, pv_lnb, pv_bh, pv_bout,
        de_Win, de_Wh, de_Wout,
        Wne, Wed, Wpe, Wpv, Wde, Fpe, Fpv);

    encode_kernel<<<1024, blk, 0, stream>>>(nodes, edges, gvec, senders, receivers,
        Wne, ne_bin, ne_bh, ne_bout,
        Wed, ed_bin, ed_bh, ed_bout, ve, ee);

    for (int step = 0; step < 2; ++step) {
        hipMemsetAsync(agg, 0, (size_t)BB * NN * 16 * sizeof(float), stream);
        edge_update_kernel<<<512, blk, 0, stream>>>(gvec, senders, receivers,
            ve, ee, agg, Wpe, pe_bin, Fpe);
        node_update_kernel<<<512, blk, 0, stream>>>(gvec, agg, ve,
            Wpv, pv_bin, Fpv);
    }

    decode_kernel<<<512, blk, 0, stream>>>(ve,
        Wde, de_bin, de_bh, de_bout, (float*)d_out);
}

// Round 10
// 313.151 us; speedup vs baseline: 1.3060x; 1.0269x over previous
//
#include <hip/hip_runtime.h>

#define BB 2
#define NN 32768
#define EN 32768

typedef unsigned int u32;
typedef __attribute__((ext_vector_type(8))) short bf16x8;
typedef __attribute__((ext_vector_type(4))) float f32x4;

union U4 { uint4 u; bf16x8 h; };

// ---------------------------------------------------------------------------
// f32 pair -> packed bf16 dword (RNE). HW instr on gfx950 when available.
// ---------------------------------------------------------------------------
#if defined(__has_builtin)
#if __has_builtin(__builtin_amdgcn_cvt_pk_bf16_f32)
#define HAVE_CVT_PK 1
#endif
#endif

#ifdef HAVE_CVT_PK
typedef __attribute__((ext_vector_type(2))) __bf16 bfv2;
__device__ __forceinline__ u32 pk2(float lo, float hi) {
    bfv2 v = __builtin_amdgcn_cvt_pk_bf16_f32(lo, hi);
    return __builtin_bit_cast(u32, v);
}
#else
__device__ __forceinline__ u32 pk2(float lo, float hi) {
    u32 a = __builtin_bit_cast(u32, lo);
    u32 b = __builtin_bit_cast(u32, hi);
    a += 0x7FFFu + ((a >> 16) & 1u);
    b += 0x7FFFu + ((b >> 16) & 1u);
    return (a >> 16) | (b & 0xFFFF0000u);
}
#endif

__device__ __forceinline__ f32x4 MF(bf16x8 a, bf16x8 b, f32x4 c) {
    return __builtin_amdgcn_mfma_f32_16x16x32_bf16(a, b, c, 0, 0, 0);
}

// ---------------------------------------------------------------------------
// LDS bank-conflict-free weight addressing.
// Logical layout: 16-dword rows; each lane reads chunk q (4 dwords) of a row.
// Unswizzled, a phase (16 lanes, fixed q, rows n..n+15) hits only 2 bank
// slots -> 8-way conflict (round 9: 1.1M SQ_LDS_BANK_CONFLICT). Swizzle
// chunk c of row R to c' = (c + (R>>1)) & 3: phase lanes spread over all 8
// slots, 2 lanes/bank = free (m136).
// ---------------------------------------------------------------------------
__device__ __forceinline__ int swz(int rowbase, int q) {
    return rowbase + (((q + (rowbase >> 5)) & 3) << 2);
}

// ---------------------------------------------------------------------------
// Layer epilogue (register-resident; LN affine pre-folded into weights).
// Weights = A-operand (m = out-feature), activations = B-operand (n = elem).
// Lane (n,q): out-feats q*4+r (D0) / 16+q*4+r (D1) of element n. Under the
// pi k-permutation pk2(y_lo[i], y_hi[i]) IS the next layer's B-frag dword i.
// ---------------------------------------------------------------------------
template<bool LN>
__device__ __forceinline__ bf16x8 transform(f32x4 D0, f32x4 D1,
                                            float4 bl, float4 bh)
{
    float y0 = fmaxf(D0[0] + bl.x, 0.f), y1 = fmaxf(D0[1] + bl.y, 0.f);
    float y2 = fmaxf(D0[2] + bl.z, 0.f), y3 = fmaxf(D0[3] + bl.w, 0.f);
    float z0 = fmaxf(D1[0] + bh.x, 0.f), z1 = fmaxf(D1[1] + bh.y, 0.f);
    float z2 = fmaxf(D1[2] + bh.z, 0.f), z3 = fmaxf(D1[3] + bh.w, 0.f);
    if (LN) {
        float s = ((y0+y1)+(y2+y3)) + ((z0+z1)+(z2+z3));
        float s2 = 0.f;
        s2 = fmaf(y0,y0,s2); s2 = fmaf(y1,y1,s2); s2 = fmaf(y2,y2,s2); s2 = fmaf(y3,y3,s2);
        s2 = fmaf(z0,z0,s2); s2 = fmaf(z1,z1,s2); s2 = fmaf(z2,z2,s2); s2 = fmaf(z3,z3,s2);
        s  += __shfl_xor(s, 16);  s  += __shfl_xor(s, 32);
        s2 += __shfl_xor(s2, 16); s2 += __shfl_xor(s2, 32);
        float mu  = s * (1.f/32.f);
        float var = fmaf(-mu, mu, s2 * (1.f/32.f));
        float rs  = rsqrtf(var + 1e-5f);
        float nt  = -mu * rs;
        y0 = fmaf(y0, rs, nt); y1 = fmaf(y1, rs, nt);
        y2 = fmaf(y2, rs, nt); y3 = fmaf(y3, rs, nt);
        z0 = fmaf(z0, rs, nt); z1 = fmaf(z1, rs, nt);
        z2 = fmaf(z2, rs, nt); z3 = fmaf(z3, rs, nt);
    }
    U4 c;
    c.u.x = pk2(y0, z0); c.u.y = pk2(y1, z1);
    c.u.z = pk2(y2, z2); c.u.w = pk2(y3, z3);
    return c.h;
}

// ---------------------------------------------------------------------------
// Block-level staging of packed weights + biases into LDS (swizzled).
// WB layout (floats): [0..32) bin | [32..1056) hidden biases | [1056..1072) out
// ---------------------------------------------------------------------------
__device__ __forceinline__ void stage_weights(
    u32* WL, float* WB, const u32* __restrict__ Wp,
    const float* __restrict__ bin, const float* __restrict__ bhid,
    const float* __restrict__ bo, int wtot, int nbo, int tid, int nthr)
{
    for (int C = tid; C * 4 < wtot; C += nthr) {
        int Cp = (C & ~3) | ((C + (C >> 3)) & 3);
        *(uint4*)(WL + Cp*4) = *(const uint4*)(Wp + C*4);
    }
    for (int i = tid; i < 1072; i += nthr) {
        float v;
        if (i < 32)         v = bin[i];
        else if (i < 1056)  v = bhid[i-32];
        else                v = (i-1056 < nbo) ? bo[i-1056] : 0.f;
        WB[i] = v;
    }
    __syncthreads();
}

// ---------------------------------------------------------------------------
// Wave-level deep MLP over TWO independent 16-element groups, weights/biases
// from LDS (swizzled reads). Depth-2 weight prefetch + depth-1 bias prefetch
// keep all ds_read latency off the per-layer critical path.
// WL (pi layout): [Bin 32 x KT*16 dw][Bh 32 x 512 dw][Bo 256 dw]
// ---------------------------------------------------------------------------
template<int KT, bool LN>
__device__ __forceinline__ void mlp_core2(
    const bf16x8* bA, const bf16x8* bB,
    const u32* WL, const float* WB,
    int n, int q, f32x4& OA, f32x4& OB)
{
    constexpr int HB = 32*KT*16;
    constexpr int BO = HB + 16384;
    U4 c;
    const f32x4 Z = {0.f,0.f,0.f,0.f};
    f32x4 A0 = Z, A1 = Z, B0 = Z, B1 = Z;
    #pragma unroll
    for (int T = 0; T < KT; ++T) {
        c.u = *(const uint4*)(WL + swz(n*(KT*16) + T*16, q));      bf16x8 a0 = c.h;
        c.u = *(const uint4*)(WL + swz((n+16)*(KT*16) + T*16, q)); bf16x8 a1 = c.h;
        A0 = MF(a0, bA[T], A0); A1 = MF(a1, bA[T], A1);
        B0 = MF(a0, bB[T], B0); B1 = MF(a1, bB[T], B1);
    }
    // prefetch layer 0/1 weights (depth-2) and layer-0 biases (depth-1)
    c.u = *(const uint4*)(WL + swz(HB + n*16, q));            bf16x8 w0 = c.h;
    c.u = *(const uint4*)(WL + swz(HB + (n+16)*16, q));       bf16x8 w1 = c.h;
    c.u = *(const uint4*)(WL + swz(HB + 512 + n*16, q));      bf16x8 x0 = c.h;
    c.u = *(const uint4*)(WL + swz(HB + 512 + (n+16)*16, q)); bf16x8 x1 = c.h;
    float4 bl  = *(const float4*)(WB + q*4);
    float4 bh  = *(const float4*)(WB + q*4 + 16);
    float4 pbl = *(const float4*)(WB + 32 + q*4);
    float4 pbh = *(const float4*)(WB + 32 + q*4 + 16);
    bf16x8 bb0 = transform<LN>(A0, A1, bl, bh);
    bf16x8 bb1 = transform<LN>(B0, B1, bl, bh);
    #pragma unroll 1
    for (int l = 0; l < 32; ++l) {
        const int lp = (l+2 < 32) ? l+2 : 31;
        c.u = *(const uint4*)(WL + swz(HB + lp*512 + n*16, q));      bf16x8 nw0 = c.h;
        c.u = *(const uint4*)(WL + swz(HB + lp*512 + (n+16)*16, q)); bf16x8 nw1 = c.h;
        const int lb_ = (l+1 < 32) ? l+1 : 31;
        float4 nbl = *(const float4*)(WB + 32 + lb_*32 + q*4);
        float4 nbh = *(const float4*)(WB + 32 + lb_*32 + q*4 + 16);
        f32x4 E0 = MF(w0, bb0, Z);
        f32x4 E1 = MF(w1, bb0, Z);
        f32x4 F0 = MF(w0, bb1, Z);
        f32x4 F1 = MF(w1, bb1, Z);
        bb0 = transform<LN>(E0, E1, pbl, pbh);
        bb1 = transform<LN>(F0, F1, pbl, pbh);
        w0 = x0; w1 = x1; x0 = nw0; x1 = nw1;
        pbl = nbl; pbh = nbh;
    }
    c.u = *(const uint4*)(WL + swz(BO + n*16, q)); bf16x8 ao = c.h;
    OA = MF(ao, bb0, Z);
    OB = MF(ao, bb1, Z);
}

// ---------------------------------------------------------------------------
// Weight packing (pi layout) + LN-beta bias folding, merged into ONE kernel.
// ---------------------------------------------------------------------------
__device__ __forceinline__ void pack_body(
    const float* __restrict__ Win, const float* __restrict__ Wh,
    const float* __restrict__ Wout, const float* __restrict__ lng,
    u32* __restrict__ dst, int din, int dout, int KP, int lb, int tid)
{
    int t = lb * 256 + tid;
    int indw = 32*(KP/2);
    int tot = indw + 16384 + 256;
    if (t >= tot) return;
    float lo, hi;
    if (t < indw) {
        int nrow = t / (KP/2), rem = t % (KP/2);
        int T = rem >> 4, d = rem & 15;
        int klo = T*32 + d, khi = klo + 16;
        lo = (klo < din) ? Win[klo*32 + nrow] : 0.f;
        hi = (khi < din) ? Win[khi*32 + nrow] : 0.f;
    } else if (t < indw + 16384) {
        int u = t - indw; int l = u >> 9; int v = u & 511;
        int nrow = v >> 4; int d = v & 15;
        lo = Wh[l*1024 + d*32 + nrow];
        hi = Wh[l*1024 + (d+16)*32 + nrow];
        if (lng) { lo *= lng[l*32 + d]; hi *= lng[l*32 + d + 16]; }
    } else {
        int u = t - indw - 16384; int nrow = u >> 4; int d = u & 15;
        lo = (nrow < dout) ? Wout[d*dout + nrow] : 0.f;
        hi = (nrow < dout) ? Wout[(d+16)*dout + nrow] : 0.f;
        if (lng) { lo *= lng[1024 + d]; hi *= lng[1024 + d + 16]; }
    }
    dst[t] = pk2(lo, hi);
}

__device__ __forceinline__ void fold_body(
    const float* __restrict__ Wh,   const float* __restrict__ bh,
    const float* __restrict__ Wout, const float* __restrict__ bout,
    const float* __restrict__ lnb,  float* __restrict__ fb, int lb, int tid)
{
    int j = lb * 256 + tid;
    if (j < 1024) {
        int l = j >> 5, jj = j & 31;
        float acc = bh[j];
        #pragma unroll
        for (int k = 0; k < 32; ++k)
            acc = fmaf(lnb[l*32 + k], Wh[l*1024 + k*32 + jj], acc);
        fb[j] = acc;
    } else if (j < 1024 + 16) {
        int jj = j - 1024;
        float acc = bout[jj];
        #pragma unroll
        for (int k = 0; k < 32; ++k)
            acc = fmaf(lnb[1024 + k], Wout[k*16 + jj], acc);
        fb[j] = acc;
    }
}

__global__ __launch_bounds__(256) void prep_kernel(
    const float* ne_Win, const float* ne_Wh, const float* ne_Wout,
    const float* ed_Win, const float* ed_Wh, const float* ed_Wout,
    const float* pe_Win, const float* pe_Wh, const float* pe_Wout,
    const float* pe_lng, const float* pe_lnb, const float* pe_bh, const float* pe_bout,
    const float* pv_Win, const float* pv_Wh, const float* pv_Wout,
    const float* pv_lng, const float* pv_lnb, const float* pv_bh, const float* pv_bout,
    const float* de_Win, const float* de_Wh, const float* de_Wout,
    u32* Wne, u32* Wed, u32* Wpe, u32* Wpv, u32* Wde,
    float* Fpe, float* Fpv)
{
    int bx = blockIdx.x, tid = threadIdx.x;
    if      (bx < 70)  pack_body(ne_Win, ne_Wh, ne_Wout, nullptr, Wne,  7, 16, 32, bx,       tid);
    else if (bx < 140) pack_body(ed_Win, ed_Wh, ed_Wout, nullptr, Wed,  5, 16, 32, bx - 70,  tid);
    else if (bx < 210) pack_body(pe_Win, pe_Wh, pe_Wout, pe_lng,  Wpe, 49, 16, 64, bx - 140, tid);
    else if (bx < 280) pack_body(pv_Win, pv_Wh, pv_Wout, pv_lng,  Wpv, 33, 16, 64, bx - 210, tid);
    else if (bx < 350) pack_body(de_Win, de_Wh, de_Wout, nullptr, Wde, 16,  3, 32, bx - 280, tid);
    else if (bx < 355) fold_body(pe_Wh, pe_bh, pe_Wout, pe_bout, pe_lnb, Fpe, bx - 350, tid);
    else               fold_body(pv_Wh, pv_bh, pv_Wout, pv_bout, pv_lnb, Fpv, bx - 355, tid);
}

// ---------------------------------------------------------------------------
// Staging helpers (one element per lane; lanes q>=2 contribute zeros).
// ---------------------------------------------------------------------------
__device__ __forceinline__ bf16x8 stage_node(
    const float* __restrict__ nodes, float g, int e, int q)
{
    uint4 w; w.x = 0u; w.y = 0u; w.z = 0u; w.w = 0u;
    if (q == 0) {
        float2 v01 = *(const float2*)(nodes + (size_t)e*6);
        float2 v23 = *(const float2*)(nodes + (size_t)e*6 + 2);
        w.x = pk2(v01.x, 0.f); w.y = pk2(v01.y, 0.f);
        w.z = pk2(v23.x, 0.f); w.w = pk2(v23.y, 0.f);
    } else if (q == 1) {
        float2 v45 = *(const float2*)(nodes + (size_t)e*6 + 4);
        w.x = pk2(v45.x, 0.f); w.y = pk2(v45.y, 0.f);
        w.z = pk2(g, 0.f);
    }
    U4 c; c.u = w; return c.h;
}

__device__ __forceinline__ bf16x8 stage_edge(
    const float* __restrict__ nodes, const float* __restrict__ edges,
    const int* __restrict__ senders, const int* __restrict__ receivers,
    int e, int b, int q)
{
    uint4 w; w.x = 0u; w.y = 0u; w.z = 0u; w.w = 0u;
    if (q < 2) {
        int s = senders[e], r = receivers[e];
        const float* ps = nodes + ((size_t)b*NN + s)*6;
        const float* pr = nodes + ((size_t)b*NN + r)*6;
        float2 s01 = *(const float2*)ps; float s2v = ps[2];
        float2 r01 = *(const float2*)pr; float r2v = pr[2];
        float r0 = s01.x - r01.x, r1 = s01.y - r01.y, r2 = s2v - r2v;
        if (q == 0) {
            w.x = pk2(edges[e], 0.f); w.y = pk2(r0, 0.f);
            w.z = pk2(r1, 0.f);       w.w = pk2(r2, 0.f);
        } else {
            w.x = pk2(sqrtf(r0*r0 + r1*r1 + r2*r2), 0.f);
        }
    }
    U4 c; c.u = w; return c.h;
}

// ---------------------------------------------------------------------------
// Kernels. Block = 512 thr = 8 waves (one weight staging per 8 waves);
// each wave owns 32 elements (two groups of 16).
// encode: 512 blocks, 73KB LDS -> 2 blocks/CU fully co-resident (4 w/SIMD).
// edge/node/decode: 256 blocks -> 1 block/CU (grid-limited).
// ---------------------------------------------------------------------------
#define WAVE_SETUP \
    const int lane = threadIdx.x & 63; \
    const int wid  = threadIdx.x >> 6; \
    const int n = lane & 15, q = lane >> 4; \
    (void)lane;

__global__ __launch_bounds__(512, 4) void encode_kernel(
    const float* __restrict__ nodes, const float* __restrict__ edges,
    const float* __restrict__ gvec,
    const int* __restrict__ senders, const int* __restrict__ receivers,
    const u32* __restrict__ Wne, const float* __restrict__ ne_bin,
    const float* __restrict__ ne_bh, const float* __restrict__ ne_bout,
    const u32* __restrict__ Wed, const float* __restrict__ ed_bin,
    const float* __restrict__ ed_bh, const float* __restrict__ ed_bout,
    float* __restrict__ ve, float* __restrict__ ee)
{
    __shared__ __align__(16) u32 SL[17152 + 1072];
    u32* WL = SL;
    float* WB = (float*)(SL + 17152);
    WAVE_SETUP
    const bool edge_stage = blockIdx.x >= 256;
    stage_weights(WL, WB,
                  edge_stage ? Wed : Wne,
                  edge_stage ? ed_bin : ne_bin,
                  edge_stage ? ed_bh : ne_bh,
                  edge_stage ? ed_bout : ne_bout,
                  17152, 16, threadIdx.x, 512);
    const int lb = edge_stage ? (blockIdx.x - 256) : blockIdx.x;
    const int e0 = (lb*8 + wid) * 32;
    const int eA = e0 + n, eB = e0 + 16 + n;
    const int bA = eA >> 15, bB = eB >> 15;
    bf16x8 aA, aB;
    if (!edge_stage) {
        aA = stage_node(nodes, gvec[bA], eA, q);
        aB = stage_node(nodes, gvec[bB], eB, q);
    } else {
        aA = stage_edge(nodes, edges, senders, receivers, eA, bA, q);
        aB = stage_edge(nodes, edges, senders, receivers, eB, bB, q);
    }
    float* dst = edge_stage ? ee : ve;
    f32x4 DA, DB;
    mlp_core2<1, false>(&aA, &aB, WL, WB, n, q, DA, DB);
    float4 bo = *(const float4*)(WB + 1056 + q*4);
    float4 st;
    st.x = fmaxf(DA[0] + bo.x, 0.f); st.y = fmaxf(DA[1] + bo.y, 0.f);
    st.z = fmaxf(DA[2] + bo.z, 0.f); st.w = fmaxf(DA[3] + bo.w, 0.f);
    *(float4*)(dst + (size_t)eA*16 + q*4) = st;
    st.x = fmaxf(DB[0] + bo.x, 0.f); st.y = fmaxf(DB[1] + bo.y, 0.f);
    st.z = fmaxf(DB[2] + bo.z, 0.f); st.w = fmaxf(DB[3] + bo.w, 0.f);
    *(float4*)(dst + (size_t)eB*16 + q*4) = st;
}

__global__ __launch_bounds__(512, 2) void edge_update_kernel(
    const float* __restrict__ gvec,
    const int* __restrict__ senders, const int* __restrict__ receivers,
    const float* __restrict__ ve, float* __restrict__ ee, float* __restrict__ agg,
    const u32* __restrict__ Wp, const float* __restrict__ bin,
    const float* __restrict__ fb)
{
    __shared__ __align__(16) u32 SL[17664 + 1072 + 8*320];
    u32* WL = SL;
    float* WB = (float*)(SL + 17664);
    WAVE_SETUP
    float* X = (float*)(SL + 18736) + wid*320;
    stage_weights(WL, WB, Wp, bin, fb, fb + 1024, 17664, 16, threadIdx.x, 512);
    const int e0 = (blockIdx.x*8 + wid) * 32;
    const int eA = e0 + n, eB = e0 + 16 + n;
    const int bA = eA >> 15, bB = eB >> 15;
    const int sA = senders[eA], rA = receivers[eA];
    const int sB = senders[eB], rB = receivers[eB];
    float gA = gvec[bA], gB = gvec[bB];
    bf16x8 aA[2], aB[2];
    {
        float4 eev = *(const float4*)(ee + (size_t)eA*16 + q*4);
        float4 vsv = *(const float4*)(ve + ((size_t)bA*NN + sA)*16 + q*4);
        float4 vrv = *(const float4*)(ve + ((size_t)bA*NN + rA)*16 + q*4);
        U4 c;
        c.u.x = pk2(eev.x, vsv.x); c.u.y = pk2(eev.y, vsv.y);
        c.u.z = pk2(eev.z, vsv.z); c.u.w = pk2(eev.w, vsv.w);
        aA[0] = c.h;
        c.u.x = pk2(vrv.x, (q == 0) ? gA : 0.f);
        c.u.y = pk2(vrv.y, 0.f); c.u.z = pk2(vrv.z, 0.f); c.u.w = pk2(vrv.w, 0.f);
        aA[1] = c.h;
    }
    {
        float4 eev = *(const float4*)(ee + (size_t)eB*16 + q*4);
        float4 vsv = *(const float4*)(ve + ((size_t)bB*NN + sB)*16 + q*4);
        float4 vrv = *(const float4*)(ve + ((size_t)bB*NN + rB)*16 + q*4);
        U4 c;
        c.u.x = pk2(eev.x, vsv.x); c.u.y = pk2(eev.y, vsv.y);
        c.u.z = pk2(eev.z, vsv.z); c.u.w = pk2(eev.w, vsv.w);
        aB[0] = c.h;
        c.u.x = pk2(vrv.x, (q == 0) ? gB : 0.f);
        c.u.y = pk2(vrv.y, 0.f); c.u.z = pk2(vrv.z, 0.f); c.u.w = pk2(vrv.w, 0.f);
        aB[1] = c.h;
    }
    f32x4 DA, DB;
    mlp_core2<2, true>(aA, aB, WL, WB, n, q, DA, DB);
    float4 bo = *(const float4*)(WB + 1056 + q*4);
    float4 stA, stB;
    stA.x = fmaxf(DA[0] + bo.x, 0.f); stA.y = fmaxf(DA[1] + bo.y, 0.f);
    stA.z = fmaxf(DA[2] + bo.z, 0.f); stA.w = fmaxf(DA[3] + bo.w, 0.f);
    stB.x = fmaxf(DB[0] + bo.x, 0.f); stB.y = fmaxf(DB[1] + bo.y, 0.f);
    stB.z = fmaxf(DB[2] + bo.z, 0.f); stB.w = fmaxf(DB[3] + bo.w, 0.f);
    *(float4*)(ee + (size_t)eA*16 + q*4) = stA;
    *(float4*)(ee + (size_t)eB*16 + q*4) = stB;
    // Coalesced atomics: transpose each group through wave-private LDS so one
    // atomic instruction hits 4 receiver lines (16 lanes share a receiver).
    *(float4*)(X + n*20 + q*4) = stA;
    #pragma unroll
    for (int rr = 0; rr < 4; ++rr) {
        int em = e0 + q*4 + rr;
        float v = X[(q*4+rr)*20 + n];
        int rc = __shfl(rA, q*4 + rr);
        atomicAdd(agg + ((size_t)(em >> 15)*NN + rc)*16 + n, v);
    }
    *(float4*)(X + n*20 + q*4) = stB;
    #pragma unroll
    for (int rr = 0; rr < 4; ++rr) {
        int em = e0 + 16 + q*4 + rr;
        float v = X[(q*4+rr)*20 + n];
        int rc = __shfl(rB, q*4 + rr);
        atomicAdd(agg + ((size_t)(em >> 15)*NN + rc)*16 + n, v);
    }
}

__global__ __launch_bounds__(512, 2) void node_update_kernel(
    const float* __restrict__ gvec,
    const float* __restrict__ agg, float* __restrict__ ve,
    const u32* __restrict__ Wp, const float* __restrict__ bin,
    const float* __restrict__ fb)
{
    __shared__ __align__(16) u32 SL[17664 + 1072];
    u32* WL = SL;
    float* WB = (float*)(SL + 17664);
    WAVE_SETUP
    stage_weights(WL, WB, Wp, bin, fb, fb + 1024, 17664, 16, threadIdx.x, 512);
    const int e0 = (blockIdx.x*8 + wid) * 32;
    const int eA = e0 + n, eB = e0 + 16 + n;
    const int bA = eA >> 15, bB = eB >> 15;
    float gA = gvec[bA], gB = gvec[bB];
    bf16x8 aA[2], aB[2];
    {
        float4 agv = *(const float4*)(agg + (size_t)eA*16 + q*4);
        float4 vev = *(const float4*)(ve  + (size_t)eA*16 + q*4);
        U4 c;
        c.u.x = pk2(agv.x, vev.x); c.u.y = pk2(agv.y, vev.y);
        c.u.z = pk2(agv.z, vev.z); c.u.w = pk2(agv.w, vev.w);
        aA[0] = c.h;
        c.u.x = (q == 0) ? pk2(gA, 0.f) : 0u;
        c.u.y = 0u; c.u.z = 0u; c.u.w = 0u;
        aA[1] = c.h;
    }
    {
        float4 agv = *(const float4*)(agg + (size_t)eB*16 + q*4);
        float4 vev = *(const float4*)(ve  + (size_t)eB*16 + q*4);
        U4 c;
        c.u.x = pk2(agv.x, vev.x); c.u.y = pk2(agv.y, vev.y);
        c.u.z = pk2(agv.z, vev.z); c.u.w = pk2(agv.w, vev.w);
        aB[0] = c.h;
        c.u.x = (q == 0) ? pk2(gB, 0.f) : 0u;
        c.u.y = 0u; c.u.z = 0u; c.u.w = 0u;
        aB[1] = c.h;
    }
    f32x4 DA, DB;
    mlp_core2<2, true>(aA, aB, WL, WB, n, q, DA, DB);
    float4 bo = *(const float4*)(WB + 1056 + q*4);
    float4 st;
    st.x = fmaxf(DA[0] + bo.x, 0.f); st.y = fmaxf(DA[1] + bo.y, 0.f);
    st.z = fmaxf(DA[2] + bo.z, 0.f); st.w = fmaxf(DA[3] + bo.w, 0.f);
    *(float4*)(ve + (size_t)eA*16 + q*4) = st;
    st.x = fmaxf(DB[0] + bo.x, 0.f); st.y = fmaxf(DB[1] + bo.y, 0.f);
    st.z = fmaxf(DB[2] + bo.z, 0.f); st.w = fmaxf(DB[3] + bo.w, 0.f);
    *(float4*)(ve + (size_t)eB*16 + q*4) = st;
}

__global__ __launch_bounds__(512, 2) void decode_kernel(
    const float* __restrict__ ve,
    const u32* __restrict__ Wp, const float* __restrict__ bin,
    const float* __restrict__ bh, const float* __restrict__ bout,
    float* __restrict__ out)
{
    __shared__ __align__(16) u32 SL[17152 + 1072];
    u32* WL = SL;
    float* WB = (float*)(SL + 17152);
    WAVE_SETUP
    stage_weights(WL, WB, Wp, bin, bh, bout, 17152, 3, threadIdx.x, 512);
    const int e0 = (blockIdx.x*8 + wid) * 32;
    const int eA = e0 + n, eB = e0 + 16 + n;
    bf16x8 aA, aB;
    {
        float4 v = *(const float4*)(ve + (size_t)eA*16 + q*4);
        U4 c;
        c.u.x = pk2(v.x, 0.f); c.u.y = pk2(v.y, 0.f);
        c.u.z = pk2(v.z, 0.f); c.u.w = pk2(v.w, 0.f);
        aA = c.h;
    }
    {
        float4 v = *(const float4*)(ve + (size_t)eB*16 + q*4);
        U4 c;
        c.u.x = pk2(v.x, 0.f); c.u.y = pk2(v.y, 0.f);
        c.u.z = pk2(v.z, 0.f); c.u.w = pk2(v.w, 0.f);
        aB = c.h;
    }
    f32x4 DA, DB;
    mlp_core2<1, false>(&aA, &aB, WL, WB, n, q, DA, DB);
    if (q == 0) {
        float b0 = WB[1056], b1 = WB[1057], b2 = WB[1058];
        out[(size_t)eA*3 + 0] = fmaxf(DA[0] + b0, 0.f);
        out[(size_t)eA*3 + 1] = fmaxf(DA[1] + b1, 0.f);
        out[(size_t)eA*3 + 2] = fmaxf(DA[2] + b2, 0.f);
        out[(size_t)eB*3 + 0] = fmaxf(DB[0] + b0, 0.f);
        out[(size_t)eB*3 + 1] = fmaxf(DB[1] + b1, 0.f);
        out[(size_t)eB*3 + 2] = fmaxf(DB[2] + b2, 0.f);
    }
}

// ---------------------------------------------------------------------------
// launch
// ---------------------------------------------------------------------------
extern "C" void kernel_launch(void* const* d_in, const int* in_sizes, int n_in,
                              void* d_out, int out_size, void* d_ws, size_t ws_size,
                              hipStream_t stream)
{
    const float* nodes     = (const float*)d_in[0];
    const float* edges     = (const float*)d_in[1];
    const float* gvec      = (const float*)d_in[2];
    const int*   senders   = (const int*)  d_in[3];
    const int*   receivers = (const int*)  d_in[4];

    const float* ne_Win  = (const float*)d_in[5];
    const float* ne_bin  = (const float*)d_in[6];
    const float* ne_Wh   = (const float*)d_in[7];
    const float* ne_bh   = (const float*)d_in[8];
    const float* ne_Wout = (const float*)d_in[9];
    const float* ne_bout = (const float*)d_in[10];

    const float* ed_Win  = (const float*)d_in[11];
    const float* ed_bin  = (const float*)d_in[12];
    const float* ed_Wh   = (const float*)d_in[13];
    const float* ed_bh   = (const float*)d_in[14];
    const float* ed_Wout = (const float*)d_in[15];
    const float* ed_bout = (const float*)d_in[16];

    const float* pe_Win  = (const float*)d_in[17];
    const float* pe_bin  = (const float*)d_in[18];
    const float* pe_Wh   = (const float*)d_in[19];
    const float* pe_bh   = (const float*)d_in[20];
    const float* pe_Wout = (const float*)d_in[21];
    const float* pe_bout = (const float*)d_in[22];
    const float* pe_lng  = (const float*)d_in[23];
    const float* pe_lnb  = (const float*)d_in[24];

    const float* pv_Win  = (const float*)d_in[25];
    const float* pv_bin  = (const float*)d_in[26];
    const float* pv_Wh   = (const float*)d_in[27];
    const float* pv_bh   = (const float*)d_in[28];
    const float* pv_Wout = (const float*)d_in[29];
    const float* pv_bout = (const float*)d_in[30];
    const float* pv_lng  = (const float*)d_in[31];
    const float* pv_lnb  = (const float*)d_in[32];

    const float* de_Win  = (const float*)d_in[33];
    const float* de_bin  = (const float*)d_in[34];
    const float* de_Wh   = (const float*)d_in[35];
    const float* de_bh   = (const float*)d_in[36];
    const float* de_Wout = (const float*)d_in[37];
    const float* de_bout = (const float*)d_in[38];

    // workspace: ve | ee | agg (4 MB each) | packed bf16 weights | folded biases
    float* ve  = (float*)d_ws;
    float* ee  = ve + (size_t)1048576;
    float* agg = ee + (size_t)1048576;
    u32* Wne = (u32*)(agg + (size_t)1048576);
    u32* Wed = Wne + 17152;
    u32* Wpe = Wed + 17152;
    u32* Wpv = Wpe + 17664;
    u32* Wde = Wpv + 17664;
    float* Fpe = (float*)(Wde + 17152);
    float* Fpv = Fpe + 1040;

    prep_kernel<<<360, dim3(256), 0, stream>>>(
        ne_Win, ne_Wh, ne_Wout,
        ed_Win, ed_Wh, ed_Wout,
        pe_Win, pe_Wh, pe_Wout, pe_lng, pe_lnb, pe_bh, pe_bout,
        pv_Win, pv_Wh, pv_Wout, pv_lng, pv_lnb, pv_bh, pv_bout,
        de_Win, de_Wh, de_Wout,
        Wne, Wed, Wpe, Wpv, Wde, Fpe, Fpv);

    const dim3 blk(512);

    encode_kernel<<<512, blk, 0, stream>>>(nodes, edges, gvec, senders, receivers,
        Wne, ne_bin, ne_bh, ne_bout,
        Wed, ed_bin, ed_bh, ed_bout, ve, ee);

    for (int step = 0; step < 2; ++step) {
        hipMemsetAsync(agg, 0, (size_t)BB * NN * 16 * sizeof(float), stream);
        edge_update_kernel<<<256, blk, 0, stream>>>(gvec, senders, receivers,
            ve, ee, agg, Wpe, pe_bin, Fpe);
        node_update_kernel<<<256, blk, 0, stream>>>(gvec, agg, ve,
            Wpv, pv_bin, Fpv);
    }

    decode_kernel<<<256, blk, 0, stream>>>(ve,
        Wde, de_bin, de_bh, de_bout, (float*)d_out);
}